// Round 12
// baseline (408.953 us; speedup 1.0000x reference)
//
#include <hip/hip_runtime.h>
#include <math.h>

// Problem constants
constexpr int Bn  = 2;
constexpr int CIN = 4;
constexpr int MQn = 1024;
constexpr int D0 = 64, D1 = 32, D2 = 16, D3 = 8;

// Output layout (floats): x [2,128,8,8,8] = 131072, q [1,2,2] = 4, k [3,2] = 6
constexpr int OUT_X = 0;
constexpr int OUT_Q = 131072;
constexpr int OUT_K = 131076;

// Workspace layout (floats). Only cnt+zerow (16 fl) need zeroing.
constexpr size_t OFF_CNT   = 0;
constexpr size_t OFF_ZERO  = 8;                    // 32B zero block for DMA padding
constexpr size_t OFF_D1    = 16;                   // (dead accumulator slots, kept as spacing)
constexpr size_t OFF_T2    = OFF_D1 + 2097152;     // t2 fp32 2*64*16^3
constexpr size_t OFF_D2    = OFF_T2 + 524288;
constexpr size_t OFF_T3    = OFF_D2 + 524288;      // t3 fp32 2*96*8^3
constexpr size_t OFF_D3    = OFF_T3 + 98304;
constexpr size_t ZERO_END  = OFF_D3 + 98304;
// non-zeroed region
constexpr size_t OFF_SCALE = 3342360;
constexpr size_t OFF_M1    = 3342368;              // 2*32^3
constexpr size_t OFF_M2    = OFF_M1 + 65536;
constexpr size_t OFF_M3    = OFF_M2 + 8192;
constexpr size_t OFF_T1    = OFF_M3 + 1024;        // 2*32*32^3
constexpr size_t OFF_Y1    = OFF_T1 + 2097152;     // xcl [b][64^3][8] bf16 hi4|lo4
constexpr size_t OFF_Y2    = OFF_Y1 + 2097152;     // (unused, kept for layout)
// channel-last bf16 buffers (sizes in floats = shorts/2)
constexpr size_t OFF_SQ1   = OFF_Y2 + 524288;      // 2*32^3*32 sh = 1048576 fl
constexpr size_t OFF_SQ2   = OFF_SQ1 + 1048576;    // 2*16^3*64 sh = 262144 fl
constexpr size_t OFF_SQ3   = OFF_SQ2 + 262144;     // 2*8^3*96 sh = 49152 fl
constexpr size_t OFF_Y3C   = OFF_SQ3 + 49152;      // 2*8^3*96 sh = 49152 fl
// (dead fp32 transposed-weight slots kept as spacing)
constexpr size_t OFF_W1T   = OFF_Y3C + 49152;      // 16000
constexpr size_t OFF_W2T   = OFF_W1T + 16000;      // 256000
constexpr size_t OFF_W3T   = OFF_W2T + 256000;     // 768000
// bf16 MFMA weights [cs][nch][tap][n32][kc2][8]
constexpr size_t OFF_WB1   = OFF_W3T + 768000;     // 128000 sh = 64000 fl
constexpr size_t OFF_WB2   = OFF_WB1 + 64000;      // 512000 sh = 256000 fl
constexpr size_t OFF_WB3   = OFF_WB2 + 256000;     // 1152000 sh = 576000 fl
constexpr size_t OFF_WB4   = OFF_WB3 + 576000;     // 1536000 sh = 768000 fl
// UNION partial buffer, time-shared by ALL split-K producers (max = conv2 18 gr)
constexpr size_t OFF_PU    = 12248736;             // 9437184 fl
// y1 planar [pl4][b][32^3 vox][16ch] bf16 (pl = cs&3; cs4/5 alias 0/1)
constexpr size_t OFF_Y1P   = OFF_PU + 9437184;     // 4*2*32768*16 sh = 2097152 fl
constexpr size_t OFF_WB2S  = OFF_Y1P + 3145728;    // w2 eff bf16 [cs6][nch2][tap][512]
constexpr size_t OFF_WB1S  = OFF_WB2S + 384000;    // conv1 [tap][n32][kc2][8]: 64000 sh
constexpr size_t OFF_WB3S  = OFF_WB1S + 32000;     // w3 eff bf16 [cs12][nch3][tap][512]: 2304000 sh
constexpr size_t OFF_Y2HL  = OFF_WB3S + 1152000;   // y2 CL [b][vox][192] bf16: 1572864 sh
// end = 27186080 floats (~109 MB)

typedef float v4f __attribute__((ext_vector_type(4)));
typedef __attribute__((ext_vector_type(8)))  short bf16x8v;
typedef __attribute__((ext_vector_type(4)))  short bf16x4v;
typedef __attribute__((ext_vector_type(16))) float f32x16v;

__device__ __forceinline__ void async_copy16(const float* g, float* l) {
    __builtin_amdgcn_global_load_lds(
        (const __attribute__((address_space(1))) void*)g,
        (__attribute__((address_space(3))) void*)l, 16, 0, 0);
}
__device__ __forceinline__ unsigned short f2bf(float f) {
    unsigned u = __float_as_uint(f);
    return (unsigned short)((u + 0x7FFFu + ((u >> 16) & 1u)) >> 16);
}
__device__ __forceinline__ float bf2f(unsigned short h) {
    return __uint_as_float((unsigned)h << 16);
}

__global__ void qmean_kernel(const float* __restrict__ QF, float* __restrict__ out_q,
                             float* __restrict__ scale) {
    int b = blockIdx.x >> 1, c = blockIdx.x & 1;
    float s = 0.f;
    for (int m = threadIdx.x; m < MQn; m += blockDim.x)
        s += QF[(b * MQn + m) * 2 + c];
    __shared__ float sh[256];
    sh[threadIdx.x] = s;
    __syncthreads();
    for (int st = 128; st > 0; st >>= 1) {
        if (threadIdx.x < st) sh[threadIdx.x] += sh[threadIdx.x + st];
        __syncthreads();
    }
    if (threadIdx.x == 0) {
        float mean = sh[0] / (float)MQn;
        out_q[b * 2 + c] = mean;
        if (c == 0) scale[b] = mean;
    }
}

// ===== R17: fused mask_pool1 + xcl: single pass over x_feat (33.5 MB once,
// not twice). Per thread = one m1 output voxel = 8 input voxels x 4 ch.
__global__ __launch_bounds__(256) void maskxcl_kernel(const float* __restrict__ xf,
        float* __restrict__ m1, float* __restrict__ c0,
        unsigned short* __restrict__ xcl) {
    int idx = blockIdx.x * 256 + threadIdx.x;   // 0..65535
    int b = idx >> 15;
    int v = idx & 32767;
    int oz = v >> 10, oy = (v >> 5) & 31, ox = v & 31;
    float cnt = 0.f, mx = 0.f;
    for (int dz = 0; dz < 2; ++dz)
        for (int dy = 0; dy < 2; ++dy)
            for (int dx = 0; dx < 2; ++dx) {
                int z = 2 * oz + dz, y = 2 * oy + dy, x = 2 * ox + dx;
                size_t s = ((size_t)z * D0 + y) * D0 + x;
                size_t base = (size_t)b * CIN * 262144 + s;
                bool occ = false;
                bf16x8v o;
#pragma unroll
                for (int c = 0; c < 4; ++c) {
                    float f = xf[base + (size_t)c * 262144];
                    occ = occ || (f != 0.f);
                    unsigned short h = f2bf(f);
                    o[c] = (short)h;
                    o[4 + c] = (short)f2bf(f - bf2f(h));
                }
                *(bf16x8v*)(xcl + ((size_t)b * 262144 + s) * 8) = o;
                if (occ) { cnt += 1.f; mx = 1.f; }
            }
    m1[idx] = mx;
    __shared__ float sh[256];
    sh[threadIdx.x] = cnt;
    __syncthreads();
    for (int st = 128; st > 0; st >>= 1) {
        if (threadIdx.x < st) sh[threadIdx.x] += sh[threadIdx.x + st];
        __syncthreads();
    }
    if (threadIdx.x == 0) atomicAdd(&c0[b], sh[0]);
}

// ===== R17: fused pool m1->m2->m3 + c1/c2 accumulation (replaces 2 launches).
// Per thread = one m3 voxel: 4^3 m1 reads, 8 m2 writes, 1 m3 write.
__global__ __launch_bounds__(256) void pool23_kernel(const float* __restrict__ m1,
        float* __restrict__ m2, float* __restrict__ m3, float* __restrict__ cnt) {
    int idx = blockIdx.x * 256 + threadIdx.x;   // 0..1023 (2*8^3)
    int b = idx >> 9;
    int v = idx & 511;
    int oz = v >> 6, oy = (v >> 3) & 7, ox = v & 7;
    float s1 = 0.f, s2 = 0.f, mx3 = 0.f;
#pragma unroll
    for (int a = 0; a < 2; ++a)
#pragma unroll
        for (int bb = 0; bb < 2; ++bb)
#pragma unroll
            for (int cc = 0; cc < 2; ++cc) {
                float mx2 = 0.f;
#pragma unroll
                for (int dz = 0; dz < 2; ++dz)
#pragma unroll
                    for (int dy = 0; dy < 2; ++dy)
#pragma unroll
                        for (int dx = 0; dx < 2; ++dx) {
                            int z = 4 * oz + 2 * a + dz, y = 4 * oy + 2 * bb + dy,
                                x = 4 * ox + 2 * cc + dx;
                            float val = m1[(((size_t)b * 32 + z) * 32 + y) * 32 + x];
                            s1 += val;
                            mx2 = fmaxf(mx2, val);
                        }
                m2[(((size_t)b * 16 + 2 * oz + a) * 16 + 2 * oy + bb) * 16 + 2 * ox + cc] = mx2;
                s2 += mx2;
                mx3 = fmaxf(mx3, mx2);
            }
    m3[idx] = mx3;
    __shared__ float sh[256][2];
    sh[threadIdx.x][0] = s1;
    sh[threadIdx.x][1] = s2;
    __syncthreads();
    for (int st = 128; st > 0; st >>= 1) {
        if (threadIdx.x < st) {
            sh[threadIdx.x][0] += sh[threadIdx.x + st][0];
            sh[threadIdx.x][1] += sh[threadIdx.x + st][1];
        }
        __syncthreads();
    }
    if (threadIdx.x == 0) {
        atomicAdd(&cnt[2 + b], sh[0][0]);
        atomicAdd(&cnt[4 + b], sh[0][1]);
    }
}

__global__ void writek_kernel(const float* __restrict__ cnt, float* __restrict__ outk) {
    int i = threadIdx.x;
    if (i < 6) {
        int row = i >> 1, b = i & 1;
        float v = (row == 0) ? cnt[4 + b] : (row == 1 ? cnt[2 + b] : cnt[b]);
        outk[i] = v;
    }
}

// ===== R17: ALL weight transforms in one kernel =====
// Segment 1 [0,ME4): bf16 MFMA weights [cs][nch][tap][n32][kc2][8]
// Segment 2: conv1 split weights ; Segment 3: conv2 split ; Segment 4: conv3 split
constexpr int MS1 = 0,        ME1 = 128000;   // gamma1 NCH1 CIN32
constexpr int MS2 = 128000,   ME2 = 640000;   // gamma2 NCH2 CIN64
constexpr int MS3 = 640000,   ME3 = 1792000;  // gamma3 NCH3 CIN96
constexpr int MS4 = 1792000,  ME4 = 3328000;  // w4     NCH4 CIN96
constexpr int W1S_N = 64000;    // 125tap * 512
constexpr int W2S_N = 768000;   // 6cs * 2nch * 125tap * 512
constexpr int W3S_N = 2304000;  // 12cs * 3nch * 125tap * 512
constexpr int WALL2 = ME4 + W1S_N;
constexpr int WALL3 = WALL2 + W2S_N;
constexpr int WALL_N = WALL3 + W3S_N;        // 6464000
__global__ __launch_bounds__(256) void wall_kernel(
        const float* __restrict__ g1, const float* __restrict__ g2,
        const float* __restrict__ g3, const float* __restrict__ w4,
        const float* __restrict__ w1, const float* __restrict__ w2,
        const float* __restrict__ w3, float* __restrict__ ws) {
    int idx = blockIdx.x * 256 + threadIdx.x;
    if (idx >= WALL_N) return;
    if (idx < ME4) {
        const float* src; unsigned short* dst; int nchn, cin, o;
        if (idx < ME1)      { src = g1; dst = (unsigned short*)(ws + OFF_WB1); nchn = 1; cin = 32; o = idx - MS1; }
        else if (idx < ME2) { src = g2; dst = (unsigned short*)(ws + OFF_WB2); nchn = 2; cin = 64; o = idx - MS2; }
        else if (idx < ME3) { src = g3; dst = (unsigned short*)(ws + OFF_WB3); nchn = 3; cin = 96; o = idx - MS3; }
        else                { src = w4; dst = (unsigned short*)(ws + OFF_WB4); nchn = 4; cin = 96; o = idx - MS4; }
        int j  = o & 7;
        int kc = (o >> 3) & 1;
        int n  = (o >> 4) & 31;
        int q  = o >> 9;
        int tap = q % 125;
        int q2  = q / 125;
        int nch = q2 % nchn;
        int cs  = q2 / nchn;
        int co = nch * 32 + n;
        int ci = cs * 16 + kc * 8 + j;
        dst[o] = f2bf(src[((size_t)co * cin + ci) * 125 + tap]);
    } else if (idx < WALL2) {
        // conv1 MFMA weights [tap][n32][kc2][8] (X frag = [hi4|lo4], kc halves share)
        int o = idx - ME4;
        int j = o & 7; int kc = (o >> 3) & 1; int n = (o >> 4) & 31; int tap = o >> 9;
        int ci = j & 3;
        unsigned short h;
        float wv = w1[((size_t)n * 4 + ci) * 125 + tap];
        unsigned short hi = f2bf(wv);
        if (kc == 0)       h = hi;
        else if (j < 4)    h = f2bf(wv - bf2f(hi));
        else               h = 0;
        ((unsigned short*)(ws + OFF_WB1S))[o] = h;
    } else if (idx < WALL3) {
        // conv2 split: e = cs*16+kc*8+j; e<64 -> Whi[e%32]; e>=64 -> Wlo[e%32]
        int o = idx - WALL2;
        int j = o & 7; int kc = (o >> 3) & 1; int n = (o >> 4) & 31; int q = o >> 9;
        int tap = q % 125; int q2 = q / 125; int c = q2 & 1; int cs = q2 >> 1;
        int co = c * 32 + n;
        int e = cs * 16 + kc * 8 + j;
        int ci = e & 31;
        float wv = w2[((size_t)co * 32 + ci) * 125 + tap];
        unsigned short h = f2bf(wv);
        if (e >= 64) h = f2bf(wv - bf2f(h));
        ((unsigned short*)(ws + OFF_WB2S))[o] = h;
    } else {
        // conv3 split: e<128 -> Whi[e%64]; e>=128 -> Wlo[e%64]
        int o = idx - WALL3;
        int j = o & 7; int kc = (o >> 3) & 1; int n = (o >> 4) & 31; int q = o >> 9;
        int tap = q % 125; int q2 = q / 125; int nch = q2 % 3; int cs = q2 / 3;
        int co = nch * 32 + n;
        int e = cs * 16 + kc * 8 + j;
        int ci = e & 63;
        float wv = w3[((size_t)co * 64 + ci) * 125 + tap];
        unsigned short h = f2bf(wv);
        if (e >= 128) h = f2bf(wv - bf2f(h));
        ((unsigned short*)(ws + OFF_WB3S))[o] = h;
    }
}

// ===== conv1 stride-2 MFMA (4->32, split-bf16, fused epilogue) =====
__global__ __launch_bounds__(256) void mconv1_s2_kernel(
    const unsigned short* __restrict__ xcl,  // [b][z][y][x][8]
    const unsigned short* __restrict__ wb,   // [tap][n32][kc2][8]
    const float* __restrict__ bias, const float* __restrict__ mask,
    const float* __restrict__ zerow,
    float* __restrict__ t1, unsigned short* __restrict__ sqcl)
{
    constexpr int DIN = 64, DOUT = 32;
    constexpr int NTX = 4, NTY = 8;
    int r = blockIdx.x;
    int tx0 = (r % NTX) * 8; r /= NTX;
    int ty0 = (r % NTY) * 4; r /= NTY;
    int tz0 = (r % 8) * 4;   int b = r / 8;

    int tid = threadIdx.x;
    int lane = tid & 63, w = tid >> 6;
    int n = lane & 31, kc = lane >> 5;
    int oz = tz0 + w, oy = ty0 + (n >> 3), ox = tx0 + (n & 7);

    f32x16v acc;
#pragma unroll
    for (int i = 0; i < 16; ++i) acc[i] = 0.f;

#pragma unroll 1
    for (int kz = 0; kz < 5; ++kz) {
        int gz = 2 * oz + kz - 2;
        bool zok = (unsigned)gz < (unsigned)DIN;
#pragma unroll 1
        for (int ky = 0; ky < 5; ++ky) {
            int gy = 2 * oy + ky - 2;
            bool zyok = zok && ((unsigned)gy < (unsigned)DIN);
            long long rowbase = (((long long)(b * DIN + gz) * DIN + gy) * DIN) * 8;
#pragma unroll
            for (int kx = 0; kx < 5; ++kx) {
                int gx = 2 * ox + kx - 2;
                bool ok = zyok && ((unsigned)gx < (unsigned)DIN);
                const unsigned short* g = ok ? xcl + (rowbase + (long long)gx * 8)
                                             : (const unsigned short*)zerow;
                bf16x8v dfrag = *(const bf16x8v*)g;
                int tap = (kz * 5 + ky) * 5 + kx;
                const unsigned short* wp = wb + ((size_t)tap << 9) + n * 16 + kc * 8;
                bf16x8v wfrag = *(const bf16x8v*)wp;
                acc = __builtin_amdgcn_mfma_f32_32x32x16_bf16(wfrag, dfrag, acc, 0, 0, 0);
            }
        }
    }

    int sp = (oz * DOUT + oy) * DOUT + ox;
    float mval = mask[b * DOUT * DOUT * DOUT + sp];
#pragma unroll
    for (int q = 0; q < 4; ++q) {
        int co0 = 8 * q + 4 * kc;
        bf16x4v s4;
#pragma unroll
        for (int j = 0; j < 4; ++j) {
            int co = co0 + j;
            float v = (acc[4 * q + j] + bias[co]) * mval;
            t1[(size_t)(b * 32 + co) * 32768 + sp] = v;
            s4[j] = (short)f2bf(v * v);
        }
        *(bf16x4v*)(sqcl + ((size_t)(b * 32768 + sp)) * 32 + co0) = s4;
    }
}

// ===== fused GDN1 epilogue -> PLANAR y1 [pl4][b][vox][16] bf16 =====
// R17: GDN1 mconv now CIG=1 -> single den partial.
__global__ __launch_bounds__(128) void gdn_cl1_kernel(const float* __restrict__ t,
        const float* __restrict__ pd, const float* __restrict__ beta,
        const float* __restrict__ scale, unsigned short* __restrict__ y1p) {
    constexpr size_t PLSZ = (size_t)Bn * 32768 * 16;   // shorts per plane
    int idx = blockIdx.x * 128 + threadIdx.x;   // < 65536 = Bn*32^3
    int sp = idx & 32767; int b = idx >> 15;
    float sc = scale[b];
    bf16x8v hi[4], lo[4];
#pragma unroll
    for (int g = 0; g < 4; ++g) {
#pragma unroll
        for (int j = 0; j < 8; ++j) {
            int ci = g * 8 + j;
            size_t p = (size_t)(b * 32 + ci) * 32768 + sp;
            float den = pd[p];
            float v = t[p] * rsqrtf(beta[ci] + den) * sc;
            unsigned short h = f2bf(v);
            hi[g][j] = (short)h;
            lo[g][j] = (short)f2bf(v - bf2f(h));
        }
    }
    size_t vo = ((size_t)b * 32768 + sp) * 16;
    *(bf16x8v*)(y1p + 0 * PLSZ + vo)     = hi[0];
    *(bf16x8v*)(y1p + 0 * PLSZ + vo + 8) = hi[1];
    *(bf16x8v*)(y1p + 1 * PLSZ + vo)     = hi[2];
    *(bf16x8v*)(y1p + 1 * PLSZ + vo + 8) = hi[3];
    *(bf16x8v*)(y1p + 2 * PLSZ + vo)     = lo[0];
    *(bf16x8v*)(y1p + 2 * PLSZ + vo + 8) = lo[1];
    *(bf16x8v*)(y1p + 3 * PLSZ + vo)     = lo[2];
    *(bf16x8v*)(y1p + 3 * PLSZ + vo + 8) = lo[3];
}

// ===== fused GDN2 epilogue + CL hi/lo/hi transform (64ch); sums 4 den partials =====
__global__ __launch_bounds__(128) void gdn_cl2_kernel(const float* __restrict__ t,
        const float* __restrict__ pd, const float* __restrict__ beta,
        const float* __restrict__ scale, unsigned short* __restrict__ yhl) {
    constexpr size_t NTOT = (size_t)Bn * 64 * 4096;
    int idx = blockIdx.x * 128 + threadIdx.x;   // < 8192 = Bn*16^3
    if (idx >= Bn * 4096) return;
    int sp = idx & 4095; int b = idx >> 12;
    float sc = scale[b];
    bf16x8v blk[24];
#pragma unroll
    for (int g = 0; g < 8; ++g) {
#pragma unroll
        for (int j = 0; j < 8; ++j) {
            int ci = g * 8 + j;
            size_t p = (size_t)(b * 64 + ci) * 4096 + sp;
            float den = pd[p] + pd[NTOT + p] + pd[2 * NTOT + p] + pd[3 * NTOT + p];
            float v = t[p] * rsqrtf(beta[ci] + den) * sc;
            unsigned short h = f2bf(v);
            blk[g][j] = (short)h;
            blk[8 + g][j] = (short)f2bf(v - bf2f(h));
            blk[16 + g][j] = (short)h;
        }
    }
    unsigned short* o = yhl + (size_t)idx * 192;
#pragma unroll
    for (int g = 0; g < 24; ++g) *(bf16x8v*)(o + g * 8) = blk[g];
}

// ===== planar-input stride-2 MFMA conv (conv2) =====
template<int COUTt, int DIN, int DOUT, int CIG, int ZSPL, int PLN>
__global__ __launch_bounds__(256) void mconv_s2p_kernel(
    const unsigned short* __restrict__ in,   // planar bf16
    const unsigned short* __restrict__ wb,   // [cs][nch][tap][n32][kc2][8]
    const float* __restrict__ zerow,
    float* __restrict__ pout)                // [zig*CIG+cs][b][co][vox] plain stores
{
    constexpr int NCH = COUTt / 32;
    constexpr int NTZ = DOUT / 4, NTY = DOUT / 4, NTX = (DOUT >= 8) ? DOUT / 8 : 1;
    constexpr int NT = NTZ * NTY * NTX * Bn;
    constexpr int VOX = DOUT * DOUT * DOUT;
    constexpr size_t PLSZ = (size_t)Bn * DIN * DIN * DIN * 16;

    int tile = blockIdx.x % NT; int rest = blockIdx.x / NT;
    int cs = rest % CIG; int zig = rest / CIG;
    int pl = cs % PLN;
    int r = tile;
    int tx0 = (r % NTX) * 8; r /= NTX;
    int ty0 = (r % NTY) * 4; r /= NTY;
    int tz0 = (r % NTZ) * 4; int b = r / NTZ;

    int tid = threadIdx.x;
    int lane = tid & 63, w = tid >> 6;
    int n = lane & 31, kc = lane >> 5;
    int oz = tz0 + w, oy = ty0 + (n >> 3), ox = tx0 + (n & 7);

    const unsigned short* inp = in + (size_t)pl * PLSZ;

    f32x16v acc[NCH];
#pragma unroll
    for (int c = 0; c < NCH; ++c)
#pragma unroll
        for (int i = 0; i < 16; ++i) acc[c][i] = 0.f;

    int kzlo, kzhi;
    if (ZSPL == 5)      { kzlo = zig;     kzhi = zig + 1; }
    else if (ZSPL == 3) { kzlo = 2 * zig; kzhi = (2 * zig + 2 < 5) ? 2 * zig + 2 : 5; }
    else                { kzlo = 0;       kzhi = 5; }
#pragma unroll 1
    for (int kz = kzlo; kz < kzhi; ++kz) {
        int gz = 2 * oz + kz - 2;
        bool zok = (unsigned)gz < (unsigned)DIN;
#pragma unroll 1
        for (int ky = 0; ky < 5; ++ky) {
            int gy = 2 * oy + ky - 2;
            bool zyok = zok && ((unsigned)gy < (unsigned)DIN);
            long long rowbase = (((long long)(b * DIN + gz) * DIN + gy) * DIN) * 16 + kc * 8;
#pragma unroll
            for (int kx = 0; kx < 5; ++kx) {
                int gx = 2 * ox + kx - 2;
                bool ok = zyok && ((unsigned)gx < (unsigned)DIN);
                const unsigned short* g = ok ? inp + (rowbase + (long long)gx * 16)
                                             : (const unsigned short*)zerow;
                bf16x8v dfrag = *(const bf16x8v*)g;
                int tap = (kz * 5 + ky) * 5 + kx;
#pragma unroll
                for (int c = 0; c < NCH; ++c) {
                    const unsigned short* wp =
                        wb + (((size_t)(cs * NCH + c) * 125 + tap) << 9) + n * 16 + kc * 8;
                    bf16x8v wfrag = *(const bf16x8v*)wp;
                    acc[c] = __builtin_amdgcn_mfma_f32_32x32x16_bf16(wfrag, dfrag, acc[c], 0, 0, 0);
                }
            }
        }
    }

    int sp = (oz * DOUT + oy) * DOUT + ox;
#pragma unroll
    for (int c = 0; c < NCH; ++c) {
#pragma unroll
        for (int rr = 0; rr < 16; ++rr) {
            int co = c * 32 + (rr & 3) + 8 * (rr >> 2) + 4 * kc;
            pout[((size_t)((zig * CIG + cs) * Bn + b) * COUTt + co) * VOX + sp] = acc[c][rr];
        }
    }
}

// ===== stride-2 MFMA conv, channel-last input (conv3) =====
template<int CINe, int COUTt, int DIN, int DOUT, int CIG, int ZSPL>
__global__ __launch_bounds__(256) void mconv_s2_kernel(
    const unsigned short* __restrict__ in,   // CL bf16 [b][z][y][x][CINe]
    const unsigned short* __restrict__ wb,   // [cs][nch][tap][n32][kc2][8]
    const float* __restrict__ zerow,
    float* __restrict__ pout)                // [zig*CIG+cs][b][co][vox] plain stores
{
    constexpr int NCH = COUTt / 32;
    constexpr int NTZ = DOUT / 4, NTY = DOUT / 4, NTX = (DOUT >= 8) ? DOUT / 8 : 1;
    constexpr int NT = NTZ * NTY * NTX * Bn;
    constexpr int VOX = DOUT * DOUT * DOUT;

    int tile = blockIdx.x % NT; int rest = blockIdx.x / NT;
    int cs = rest % CIG; int zig = rest / CIG;
    int r = tile;
    int tx0 = (r % NTX) * 8; r /= NTX;
    int ty0 = (r % NTY) * 4; r /= NTY;
    int tz0 = (r % NTZ) * 4; int b = r / NTZ;

    int tid = threadIdx.x;
    int lane = tid & 63, w = tid >> 6;
    int n = lane & 31, kc = lane >> 5;
    int oz = tz0 + w, oy = ty0 + (n >> 3), ox = tx0 + (n & 7);

    f32x16v acc[NCH];
#pragma unroll
    for (int c = 0; c < NCH; ++c)
#pragma unroll
        for (int i = 0; i < 16; ++i) acc[c][i] = 0.f;

    int kzlo, kzhi;
    if (ZSPL == 5)      { kzlo = zig;     kzhi = zig + 1; }
    else if (ZSPL == 3) { kzlo = 2 * zig; kzhi = (2 * zig + 2 < 5) ? 2 * zig + 2 : 5; }
    else                { kzlo = 0;       kzhi = 5; }
#pragma unroll 1
    for (int kz = kzlo; kz < kzhi; ++kz) {
        int gz = 2 * oz + kz - 2;
        bool zok = (unsigned)gz < (unsigned)DIN;
#pragma unroll 1
        for (int ky = 0; ky < 5; ++ky) {
            int gy = 2 * oy + ky - 2;
            bool zyok = zok && ((unsigned)gy < (unsigned)DIN);
            long long rowbase = (((long long)(b * DIN + gz) * DIN + gy) * DIN) * CINe
                                + cs * 16 + kc * 8;
#pragma unroll
            for (int kx = 0; kx < 5; ++kx) {
                int gx = 2 * ox + kx - 2;
                bool ok = zyok && ((unsigned)gx < (unsigned)DIN);
                const unsigned short* g = ok ? in + (rowbase + (long long)gx * CINe)
                                             : (const unsigned short*)zerow;
                bf16x8v dfrag = *(const bf16x8v*)g;
                int tap = (kz * 5 + ky) * 5 + kx;
#pragma unroll
                for (int c = 0; c < NCH; ++c) {
                    const unsigned short* wp =
                        wb + (((size_t)(cs * NCH + c) * 125 + tap) << 9) + n * 16 + kc * 8;
                    bf16x8v wfrag = *(const bf16x8v*)wp;
                    acc[c] = __builtin_amdgcn_mfma_f32_32x32x16_bf16(wfrag, dfrag, acc[c], 0, 0, 0);
                }
            }
        }
    }

    int sp = (oz * DOUT + oy) * DOUT + ox;
#pragma unroll
    for (int c = 0; c < NCH; ++c) {
#pragma unroll
        for (int rr = 0; rr < 16; ++rr) {
            int co = c * 32 + (rr & 3) + 8 * (rr >> 2) + 4 * kc;
            pout[((size_t)((zig * CIG + cs) * Bn + b) * COUTt + co) * VOX + sp] = acc[c][rr];
        }
    }
}

// reduce split-K partials + bias + mask -> t fp32 NCDHW, and sq CL bf16
template<int CS, int COUTt, int VOX>
__global__ __launch_bounds__(256) void red_epi_kernel(const float* __restrict__ P,
        const float* __restrict__ bias, const float* __restrict__ mask,
        float* __restrict__ buf, unsigned short* __restrict__ sqcl) {
    constexpr int NTOT = Bn * COUTt * VOX;
    int idx = blockIdx.x * 256 + threadIdx.x;
    if (idx >= NTOT) return;
    int sp = idx % VOX;
    int co = (idx / VOX) % COUTt;
    int b = idx / (VOX * COUTt);
    float s = 0.f;
#pragma unroll
    for (int k = 0; k < CS; ++k) s += P[(size_t)k * NTOT + idx];
    float v = (s + bias[co]) * mask[b * VOX + sp];
    buf[idx] = v;
    sqcl[((size_t)b * VOX + sp) * COUTt + co] = f2bf(v * v);
}

// ===== MFMA conv (stride-1): GDN denominators + conv4 =====
// Plain-store partials [g][b][co][vox]. R17: CSPB = cs-groups per block —
// CIG < CINt/16 stages CSPB*16 channels and loops cs internally (GDN1: CIG=1
// -> 1 partial group instead of 2, halving partial write + read traffic).
template<int CINt, int COUTt, int Dd, int TZ, int YB, int CIG, int ZSPL>
__global__ __launch_bounds__(256) void mconv_kernel(
    const unsigned short* __restrict__ in,   // CL bf16 [b][z][y][x][CINt]
    const unsigned short* __restrict__ wb,
    const float* __restrict__ zerow,
    float* __restrict__ pout)                // [g][b][co][vox] plain stores
{
    constexpr int NCH = COUTt / 32;
    constexpr int CSPB = (CINt / 16) / CIG;    // cs-groups per block
    constexpr int UPV = 2 * CSPB;              // 16B units per voxel
    constexpr int CHS = CSPB * 16;             // shorts per voxel in LDS
    constexpr int LZ = TZ + 4, LYH = YB * 4 + 4, LXH = 12;
    constexpr int HV = LZ * LYH * LXH;
    constexpr int UN = UPV * HV;               // 16B units
    constexpr int NLOAD = (UN + 255) / 256;
    constexpr int NTZ = Dd / TZ, NTY = Dd / (YB * 4), NTX = Dd / 8;
    constexpr int NT = NTZ * NTY * NTX * Bn;
    constexpr int VOX = Dd * Dd * Dd;
    __shared__ unsigned short lds[NLOAD * 256 * 8];

    int bid = blockIdx.x;
    int tile = bid % NT; int rest = bid / NT;
    int cs = rest % CIG; int zig = rest / CIG;
    int r = tile;
    int tx0 = (r % NTX) * 8; r /= NTX;
    int ty0 = (r % NTY) * (YB * 4); r /= NTY;
    int tz0 = (r % NTZ) * TZ; int b = r / NTZ;

    int tid = threadIdx.x;
    int iz0 = tz0 - 2, iy0 = ty0 - 2, ix0 = tx0 - 2;
#pragma unroll
    for (int k = 0; k < NLOAD; ++k) {
        int u = tid + k * 256;
        int v = u / UPV, part = u % UPV;
        int lx = v % LXH; int t = v / LXH;
        int ly = t % LYH, lz = t / LYH;
        int gz = iz0 + lz, gy = iy0 + ly, gx = ix0 + lx;
        bool valid = (v < HV) &&
                     (unsigned)gz < (unsigned)Dd && (unsigned)gy < (unsigned)Dd &&
                     (unsigned)gx < (unsigned)Dd;
        const unsigned short* g = valid
            ? in + ((((size_t)b * Dd + gz) * Dd + gy) * Dd + gx) * CINt + cs * CHS + part * 8
            : (const unsigned short*)zerow;
        async_copy16((const float*)g, (float*)&lds[(size_t)u * 8]);
    }
    __syncthreads();

    int lane = tid & 63, w = tid >> 6;
    int zz = (YB == 1) ? w : (w >> 1);
    int yb = (YB == 1) ? 0 : (w & 1);
    int n = lane & 31, kc = lane >> 5;
    int vy = yb * 4 + (n >> 3), vx = n & 7;

    f32x16v acc[NCH];
#pragma unroll
    for (int c = 0; c < NCH; ++c)
#pragma unroll
        for (int i = 0; i < 16; ++i) acc[c][i] = 0.f;

    int kzlo = (ZSPL == 5) ? zig : 0;
    int kzhi = (ZSPL == 5) ? zig + 1 : 5;
#pragma unroll 1
    for (int csl = 0; csl < CSPB; ++csl) {
        int csabs = cs * CSPB + csl;
#pragma unroll 1
        for (int kz = kzlo; kz < kzhi; ++kz) {
#pragma unroll 1
            for (int ky = 0; ky < 5; ++ky) {
                int hvrow = ((zz + kz) * LYH + (vy + ky)) * LXH + vx;
#pragma unroll
                for (int kx = 0; kx < 5; ++kx) {
                    bf16x8v dfrag =
                        *(const bf16x8v*)&lds[(size_t)(hvrow + kx) * CHS + csl * 16 + kc * 8];
                    int tap = (kz * 5 + ky) * 5 + kx;
#pragma unroll
                    for (int c = 0; c < NCH; ++c) {
                        const unsigned short* wp =
                            wb + (((size_t)(csabs * NCH + c) * 125 + tap) << 9) + n * 16 + kc * 8;
                        bf16x8v wfrag = *(const bf16x8v*)wp;
                        acc[c] = __builtin_amdgcn_mfma_f32_32x32x16_bf16(wfrag, dfrag, acc[c], 0, 0, 0);
                    }
                }
            }
        }
    }

    int g = rest;                            // zig*CIG + cs
    int sp = ((tz0 + zz) * Dd + (ty0 + vy)) * Dd + (tx0 + vx);
#pragma unroll
    for (int c = 0; c < NCH; ++c) {
#pragma unroll
        for (int rr = 0; rr < 16; ++rr) {
            int co = c * 32 + (rr & 3) + 8 * (rr >> 2) + 4 * kc;
            pout[((size_t)(g * Bn + b) * COUTt + co) * VOX + sp] = acc[c][rr];
        }
    }
}

// GDN3 epilogue: sum G den partials, rsqrt, scale -> y3 CL bf16
template<int G, int COUTt, int DOUT>
__global__ __launch_bounds__(256) void gdn_red_cl_kernel(const float* __restrict__ t,
        const float* __restrict__ pd, const float* __restrict__ beta,
        const float* __restrict__ scale, unsigned short* __restrict__ ycl) {
    constexpr int VOX = DOUT * DOUT * DOUT;
    constexpr int NTOT = Bn * COUTt * VOX;
    int idx = blockIdx.x * 256 + threadIdx.x;
    if (idx >= NTOT) return;
    int sp = idx % VOX;
    int co = (idx / VOX) % COUTt;
    int b = idx / (VOX * COUTt);
    float den = 0.f;
#pragma unroll
    for (int k = 0; k < G; ++k) den += pd[(size_t)k * NTOT + idx];
    float v = t[idx] * rsqrtf(beta[co] + den) * scale[b];
    ycl[((size_t)b * VOX + sp) * COUTt + co] = f2bf(v);
}

// conv4 epilogue: sum G conv partials + bias + mask -> out fp32
template<int G, int COUTt, int DOUT>
__global__ __launch_bounds__(256) void conv_red_kernel(const float* __restrict__ pc,
        const float* __restrict__ bias, const float* __restrict__ mask,
        float* __restrict__ outx) {
    constexpr int VOX = DOUT * DOUT * DOUT;
    constexpr int NTOT = Bn * COUTt * VOX;
    int idx = blockIdx.x * 256 + threadIdx.x;
    if (idx >= NTOT) return;
    int sp = idx % VOX;
    int co = (idx / VOX) % COUTt;
    int b = idx / (VOX * COUTt);
    float s = 0.f;
#pragma unroll
    for (int k = 0; k < G; ++k) s += pc[(size_t)k * NTOT + idx];
    outx[idx] = (s + bias[co]) * mask[b * VOX + sp];
}

extern "C" void kernel_launch(void* const* d_in, const int* in_sizes, int n_in,
                              void* d_out, int out_size, void* d_ws, size_t ws_size,
                              hipStream_t stream) {
    const float* x_feat = (const float*)d_in[0];
    const float* QF     = (const float*)d_in[2];
    const float* w1 = (const float*)d_in[3];  const float* b1 = (const float*)d_in[4];
    const float* w2 = (const float*)d_in[5];  const float* b2 = (const float*)d_in[6];
    const float* w3 = (const float*)d_in[7];  const float* b3 = (const float*)d_in[8];
    const float* w4 = (const float*)d_in[9];  const float* b4 = (const float*)d_in[10];
    const float* beta1 = (const float*)d_in[11]; const float* gamma1 = (const float*)d_in[12];
    const float* beta2 = (const float*)d_in[13]; const float* gamma2 = (const float*)d_in[14];
    const float* beta3 = (const float*)d_in[15]; const float* gamma3 = (const float*)d_in[16];

    float* out = (float*)d_out;
    float* ws = (float*)d_ws;
    float* cnt   = ws + OFF_CNT;
    float* zerow = ws + OFF_ZERO;
    float* scale = ws + OFF_SCALE;
    float* m1 = ws + OFF_M1;  float* m2 = ws + OFF_M2;  float* m3 = ws + OFF_M3;
    float* t1 = ws + OFF_T1;
    float* t2 = ws + OFF_T2;
    float* t3 = ws + OFF_T3;
    float* pu = ws + OFF_PU;            // union partial buffer (all split-K producers)
    unsigned short* sq1 = (unsigned short*)(ws + OFF_SQ1);
    unsigned short* sq2 = (unsigned short*)(ws + OFF_SQ2);
    unsigned short* sq3 = (unsigned short*)(ws + OFF_SQ3);
    unsigned short* y3c = (unsigned short*)(ws + OFF_Y3C);
    unsigned short* y1p = (unsigned short*)(ws + OFF_Y1P);
    unsigned short* y2hl = (unsigned short*)(ws + OFF_Y2HL);
    unsigned short* xcl = (unsigned short*)(ws + OFF_Y1);
    unsigned short* wb1 = (unsigned short*)(ws + OFF_WB1);
    unsigned short* wb2 = (unsigned short*)(ws + OFF_WB2);
    unsigned short* wb3 = (unsigned short*)(ws + OFF_WB3);
    unsigned short* wb4 = (unsigned short*)(ws + OFF_WB4);
    unsigned short* wb1s = (unsigned short*)(ws + OFF_WB1S);
    unsigned short* wb2s = (unsigned short*)(ws + OFF_WB2S);
    unsigned short* wb3s = (unsigned short*)(ws + OFF_WB3S);

    // Only cnt (pool accumulators) + zerow need zeroing; all partials are
    // plain-store-then-reduce, and out is fully overwritten.
    hipMemsetAsync(ws, 0, 16 * sizeof(float), stream);

    qmean_kernel<<<4, 256, 0, stream>>>(QF, out + OUT_Q, scale);
    // fused mask + xcl (single x_feat pass) ; fused pool m2+m3 ; k write
    maskxcl_kernel<<<256, 256, 0, stream>>>(x_feat, m1, cnt + 0, xcl);
    pool23_kernel<<<4, 256, 0, stream>>>(m1, m2, m3, cnt);
    writek_kernel<<<1, 64, 0, stream>>>(cnt, out + OUT_K);

    // all weight transforms in one launch
    wall_kernel<<<(WALL_N + 255) / 256, 256, 0, stream>>>(
        gamma1, gamma2, gamma3, w4, w1, w2, w3, ws);

    // Stage 1: conv1 MFMA s2 split-bf16 (K=16, fused epi -> t1 + sq1CL) ;
    //          GDN1 MFMA CIG=1 (CSPB=2, 1 den partial) ; gdn_cl1 -> PLANAR y1p
    mconv1_s2_kernel<<<512, 256, 0, stream>>>(xcl, wb1s, b1, m1, zerow, t1, sq1);
    mconv_kernel<32, 32, 32, 4, 1, 1, 1>
        <<<512, 256, 0, stream>>>(sq1, wb1, zerow, pu);
    gdn_cl1_kernel<<<512, 128, 0, stream>>>(t1, pu, beta1, scale, y1p);

    // Stage 2: conv2 MFMA s2 split-bf16, PLANAR gather (cs x6 -> pl=cs&3,
    //          kz-pairs x3, 1152 blocks) ; reduce 18 + epi ; GDN2 MFMA -> 4
    //          partials ; gdn_cl2 -> y2hl
    mconv_s2p_kernel<64, 32, 16, 6, 3, 4>
        <<<64 * 6 * 3, 256, 0, stream>>>(y1p, wb2s, zerow, pu);
    red_epi_kernel<18, 64, 4096><<<2048, 256, 0, stream>>>(pu, b2, m2, t2, sq2);
    mconv_kernel<64, 64, 16, 4, 1, 4, 1>
        <<<256, 256, 0, stream>>>(sq2, wb2, zerow, pu);
    gdn_cl2_kernel<<<64, 128, 0, stream>>>(t2, pu, beta2, scale, y2hl);

    // Stage 3: conv3 MFMA s2 split-bf16 (cs x12, kz x5) -> pu ; reduce 60 + epi ;
    //          GDN3 MFMA -> 30 partials (pu) ; gdn_red_cl sums -> y3 CL bf16
    mconv_s2_kernel<192, 96, 16, 8, 12, 5>
        <<<8 * 12 * 5, 256, 0, stream>>>(y2hl, wb3s, zerow, pu);
    red_epi_kernel<60, 96, 512><<<384, 256, 0, stream>>>(pu, b3, m3, t3, sq3);
    mconv_kernel<96, 96, 8, 2, 2, 6, 5>
        <<<240, 256, 0, stream>>>(sq3, wb3, zerow, pu);
    gdn_red_cl_kernel<30, 96, 8><<<384, 256, 0, stream>>>(t3, pu, beta3, scale, y3c);

    // Stage 4: conv4 MFMA (96->128, s1) -> 30 partials (pu) ;
    //          conv_red sums + bias + mask -> out
    mconv_kernel<96, 128, 8, 2, 2, 6, 5>
        <<<240, 256, 0, stream>>>(y3c, wb4, zerow, pu);
    conv_red_kernel<30, 128, 8><<<512, 256, 0, stream>>>(pu, b4, m3, out + OUT_X);
}

// Round 13
// 405.456 us; speedup vs baseline: 1.0086x; 1.0086x over previous
//
#include <hip/hip_runtime.h>
#include <math.h>

// Problem constants
constexpr int Bn  = 2;
constexpr int CIN = 4;
constexpr int MQn = 1024;
constexpr int D0 = 64, D1 = 32, D2 = 16, D3 = 8;

// Output layout (floats): x [2,128,8,8,8] = 131072, q [1,2,2] = 4, k [3,2] = 6
constexpr int OUT_X = 0;
constexpr int OUT_Q = 131072;
constexpr int OUT_K = 131076;

// Workspace layout (floats). Only cnt+zerow (16 fl) need zeroing.
constexpr size_t OFF_CNT   = 0;
constexpr size_t OFF_ZERO  = 8;                    // 32B zero block for DMA padding
constexpr size_t OFF_D1    = 16;                   // (dead accumulator slots, kept as spacing)
constexpr size_t OFF_T2    = OFF_D1 + 2097152;     // t2 fp32 2*64*16^3
constexpr size_t OFF_D2    = OFF_T2 + 524288;
constexpr size_t OFF_T3    = OFF_D2 + 524288;      // t3 fp32 2*96*8^3
constexpr size_t OFF_D3    = OFF_T3 + 98304;
constexpr size_t ZERO_END  = OFF_D3 + 98304;
// non-zeroed region
constexpr size_t OFF_SCALE = 3342360;
constexpr size_t OFF_M1    = 3342368;              // 2*32^3
constexpr size_t OFF_M2    = OFF_M1 + 65536;
constexpr size_t OFF_M3    = OFF_M2 + 8192;
constexpr size_t OFF_T1    = OFF_M3 + 1024;        // 2*32*32^3
constexpr size_t OFF_Y1    = OFF_T1 + 2097152;     // xcl [b][64^3][8] bf16 hi4|lo4
constexpr size_t OFF_Y2    = OFF_Y1 + 2097152;     // (unused, kept for layout)
// channel-last bf16 buffers (sizes in floats = shorts/2)
constexpr size_t OFF_SQ1   = OFF_Y2 + 524288;      // 2*32^3*32 sh = 1048576 fl
constexpr size_t OFF_SQ2   = OFF_SQ1 + 1048576;    // 2*16^3*64 sh = 262144 fl
constexpr size_t OFF_SQ3   = OFF_SQ2 + 262144;     // 2*8^3*96 sh = 49152 fl
constexpr size_t OFF_Y3C   = OFF_SQ3 + 49152;      // 2*8^3*96 sh = 49152 fl
// (dead fp32 transposed-weight slots kept as spacing)
constexpr size_t OFF_W1T   = OFF_Y3C + 49152;      // 16000
constexpr size_t OFF_W2T   = OFF_W1T + 16000;      // 256000
constexpr size_t OFF_W3T   = OFF_W2T + 256000;     // 768000
// bf16 MFMA weights [cs][nch][tap][n32][kc2][8]
constexpr size_t OFF_WB1   = OFF_W3T + 768000;     // 128000 sh = 64000 fl
constexpr size_t OFF_WB2   = OFF_WB1 + 64000;      // 512000 sh = 256000 fl
constexpr size_t OFF_WB3   = OFF_WB2 + 256000;     // 1152000 sh = 576000 fl
constexpr size_t OFF_WB4   = OFF_WB3 + 576000;     // 1536000 sh = 768000 fl
// UNION partial buffer, time-shared by ALL split-K producers (max = conv2 18 gr)
constexpr size_t OFF_PU    = 12248736;             // 9437184 fl
// y1 planar [pl4][b][32^3 vox][16ch] bf16 (pl = cs&3; cs4/5 alias 0/1)
constexpr size_t OFF_Y1P   = OFF_PU + 9437184;     // 4*2*32768*16 sh = 2097152 fl
constexpr size_t OFF_WB2S  = OFF_Y1P + 3145728;    // w2 eff bf16 [cs6][nch2][tap][512]
constexpr size_t OFF_WB1S  = OFF_WB2S + 384000;    // conv1 [tap][n32][kc2][8]: 64000 sh
constexpr size_t OFF_WB3S  = OFF_WB1S + 32000;     // w3 eff bf16 [cs12][nch3][tap][512]: 2304000 sh
constexpr size_t OFF_Y2HL  = OFF_WB3S + 1152000;   // y2 CL [b][vox][192] bf16: 1572864 sh
// end = 27186080 floats (~109 MB)

typedef float v4f __attribute__((ext_vector_type(4)));
typedef __attribute__((ext_vector_type(8)))  short bf16x8v;
typedef __attribute__((ext_vector_type(4)))  short bf16x4v;
typedef __attribute__((ext_vector_type(16))) float f32x16v;

__device__ __forceinline__ void async_copy16(const float* g, float* l) {
    __builtin_amdgcn_global_load_lds(
        (const __attribute__((address_space(1))) void*)g,
        (__attribute__((address_space(3))) void*)l, 16, 0, 0);
}
__device__ __forceinline__ unsigned short f2bf(float f) {
    unsigned u = __float_as_uint(f);
    return (unsigned short)((u + 0x7FFFu + ((u >> 16) & 1u)) >> 16);
}
__device__ __forceinline__ float bf2f(unsigned short h) {
    return __uint_as_float((unsigned)h << 16);
}

__global__ void qmean_kernel(const float* __restrict__ QF, float* __restrict__ out_q,
                             float* __restrict__ scale) {
    int b = blockIdx.x >> 1, c = blockIdx.x & 1;
    float s = 0.f;
    for (int m = threadIdx.x; m < MQn; m += blockDim.x)
        s += QF[(b * MQn + m) * 2 + c];
    __shared__ float sh[256];
    sh[threadIdx.x] = s;
    __syncthreads();
    for (int st = 128; st > 0; st >>= 1) {
        if (threadIdx.x < st) sh[threadIdx.x] += sh[threadIdx.x + st];
        __syncthreads();
    }
    if (threadIdx.x == 0) {
        float mean = sh[0] / (float)MQn;
        out_q[b * 2 + c] = mean;
        if (c == 0) scale[b] = mean;
    }
}

// ===== fused mask_pool1 + xcl: single pass over x_feat =====
__global__ __launch_bounds__(256) void maskxcl_kernel(const float* __restrict__ xf,
        float* __restrict__ m1, float* __restrict__ c0,
        unsigned short* __restrict__ xcl) {
    int idx = blockIdx.x * 256 + threadIdx.x;   // 0..65535
    int b = idx >> 15;
    int v = idx & 32767;
    int oz = v >> 10, oy = (v >> 5) & 31, ox = v & 31;
    float cnt = 0.f, mx = 0.f;
    for (int dz = 0; dz < 2; ++dz)
        for (int dy = 0; dy < 2; ++dy)
            for (int dx = 0; dx < 2; ++dx) {
                int z = 2 * oz + dz, y = 2 * oy + dy, x = 2 * ox + dx;
                size_t s = ((size_t)z * D0 + y) * D0 + x;
                size_t base = (size_t)b * CIN * 262144 + s;
                bool occ = false;
                bf16x8v o;
#pragma unroll
                for (int c = 0; c < 4; ++c) {
                    float f = xf[base + (size_t)c * 262144];
                    occ = occ || (f != 0.f);
                    unsigned short h = f2bf(f);
                    o[c] = (short)h;
                    o[4 + c] = (short)f2bf(f - bf2f(h));
                }
                *(bf16x8v*)(xcl + ((size_t)b * 262144 + s) * 8) = o;
                if (occ) { cnt += 1.f; mx = 1.f; }
            }
    m1[idx] = mx;
    __shared__ float sh[256];
    sh[threadIdx.x] = cnt;
    __syncthreads();
    for (int st = 128; st > 0; st >>= 1) {
        if (threadIdx.x < st) sh[threadIdx.x] += sh[threadIdx.x + st];
        __syncthreads();
    }
    if (threadIdx.x == 0) atomicAdd(&c0[b], sh[0]);
}

// ===== fused pool m1->m2->m3 + c1/c2 accumulation =====
__global__ __launch_bounds__(256) void pool23_kernel(const float* __restrict__ m1,
        float* __restrict__ m2, float* __restrict__ m3, float* __restrict__ cnt) {
    int idx = blockIdx.x * 256 + threadIdx.x;   // 0..1023 (2*8^3)
    int b = idx >> 9;
    int v = idx & 511;
    int oz = v >> 6, oy = (v >> 3) & 7, ox = v & 7;
    float s1 = 0.f, s2 = 0.f, mx3 = 0.f;
#pragma unroll
    for (int a = 0; a < 2; ++a)
#pragma unroll
        for (int bb = 0; bb < 2; ++bb)
#pragma unroll
            for (int cc = 0; cc < 2; ++cc) {
                float mx2 = 0.f;
#pragma unroll
                for (int dz = 0; dz < 2; ++dz)
#pragma unroll
                    for (int dy = 0; dy < 2; ++dy)
#pragma unroll
                        for (int dx = 0; dx < 2; ++dx) {
                            int z = 4 * oz + 2 * a + dz, y = 4 * oy + 2 * bb + dy,
                                x = 4 * ox + 2 * cc + dx;
                            float val = m1[(((size_t)b * 32 + z) * 32 + y) * 32 + x];
                            s1 += val;
                            mx2 = fmaxf(mx2, val);
                        }
                m2[(((size_t)b * 16 + 2 * oz + a) * 16 + 2 * oy + bb) * 16 + 2 * ox + cc] = mx2;
                s2 += mx2;
                mx3 = fmaxf(mx3, mx2);
            }
    m3[idx] = mx3;
    __shared__ float sh[256][2];
    sh[threadIdx.x][0] = s1;
    sh[threadIdx.x][1] = s2;
    __syncthreads();
    for (int st = 128; st > 0; st >>= 1) {
        if (threadIdx.x < st) {
            sh[threadIdx.x][0] += sh[threadIdx.x + st][0];
            sh[threadIdx.x][1] += sh[threadIdx.x + st][1];
        }
        __syncthreads();
    }
    if (threadIdx.x == 0) {
        atomicAdd(&cnt[2 + b], sh[0][0]);
        atomicAdd(&cnt[4 + b], sh[0][1]);
    }
}

__global__ void writek_kernel(const float* __restrict__ cnt, float* __restrict__ outk) {
    int i = threadIdx.x;
    if (i < 6) {
        int row = i >> 1, b = i & 1;
        float v = (row == 0) ? cnt[4 + b] : (row == 1 ? cnt[2 + b] : cnt[b]);
        outk[i] = v;
    }
}

// ===== ALL weight transforms in one kernel =====
constexpr int MS1 = 0,        ME1 = 128000;   // gamma1 NCH1 CIN32
constexpr int MS2 = 128000,   ME2 = 640000;   // gamma2 NCH2 CIN64
constexpr int MS3 = 640000,   ME3 = 1792000;  // gamma3 NCH3 CIN96
constexpr int MS4 = 1792000,  ME4 = 3328000;  // w4     NCH4 CIN96
constexpr int W1S_N = 64000;    // 125tap * 512
constexpr int W2S_N = 768000;   // 6cs * 2nch * 125tap * 512
constexpr int W3S_N = 2304000;  // 12cs * 3nch * 125tap * 512
constexpr int WALL2 = ME4 + W1S_N;
constexpr int WALL3 = WALL2 + W2S_N;
constexpr int WALL_N = WALL3 + W3S_N;        // 6464000
__global__ __launch_bounds__(256) void wall_kernel(
        const float* __restrict__ g1, const float* __restrict__ g2,
        const float* __restrict__ g3, const float* __restrict__ w4,
        const float* __restrict__ w1, const float* __restrict__ w2,
        const float* __restrict__ w3, float* __restrict__ ws) {
    int idx = blockIdx.x * 256 + threadIdx.x;
    if (idx >= WALL_N) return;
    if (idx < ME4) {
        const float* src; unsigned short* dst; int nchn, cin, o;
        if (idx < ME1)      { src = g1; dst = (unsigned short*)(ws + OFF_WB1); nchn = 1; cin = 32; o = idx - MS1; }
        else if (idx < ME2) { src = g2; dst = (unsigned short*)(ws + OFF_WB2); nchn = 2; cin = 64; o = idx - MS2; }
        else if (idx < ME3) { src = g3; dst = (unsigned short*)(ws + OFF_WB3); nchn = 3; cin = 96; o = idx - MS3; }
        else                { src = w4; dst = (unsigned short*)(ws + OFF_WB4); nchn = 4; cin = 96; o = idx - MS4; }
        int j  = o & 7;
        int kc = (o >> 3) & 1;
        int n  = (o >> 4) & 31;
        int q  = o >> 9;
        int tap = q % 125;
        int q2  = q / 125;
        int nch = q2 % nchn;
        int cs  = q2 / nchn;
        int co = nch * 32 + n;
        int ci = cs * 16 + kc * 8 + j;
        dst[o] = f2bf(src[((size_t)co * cin + ci) * 125 + tap]);
    } else if (idx < WALL2) {
        int o = idx - ME4;
        int j = o & 7; int kc = (o >> 3) & 1; int n = (o >> 4) & 31; int tap = o >> 9;
        int ci = j & 3;
        unsigned short h;
        float wv = w1[((size_t)n * 4 + ci) * 125 + tap];
        unsigned short hi = f2bf(wv);
        if (kc == 0)       h = hi;
        else if (j < 4)    h = f2bf(wv - bf2f(hi));
        else               h = 0;
        ((unsigned short*)(ws + OFF_WB1S))[o] = h;
    } else if (idx < WALL3) {
        int o = idx - WALL2;
        int j = o & 7; int kc = (o >> 3) & 1; int n = (o >> 4) & 31; int q = o >> 9;
        int tap = q % 125; int q2 = q / 125; int c = q2 & 1; int cs = q2 >> 1;
        int co = c * 32 + n;
        int e = cs * 16 + kc * 8 + j;
        int ci = e & 31;
        float wv = w2[((size_t)co * 32 + ci) * 125 + tap];
        unsigned short h = f2bf(wv);
        if (e >= 64) h = f2bf(wv - bf2f(h));
        ((unsigned short*)(ws + OFF_WB2S))[o] = h;
    } else {
        int o = idx - WALL3;
        int j = o & 7; int kc = (o >> 3) & 1; int n = (o >> 4) & 31; int q = o >> 9;
        int tap = q % 125; int q2 = q / 125; int nch = q2 % 3; int cs = q2 / 3;
        int co = nch * 32 + n;
        int e = cs * 16 + kc * 8 + j;
        int ci = e & 63;
        float wv = w3[((size_t)co * 64 + ci) * 125 + tap];
        unsigned short h = f2bf(wv);
        if (e >= 128) h = f2bf(wv - bf2f(h));
        ((unsigned short*)(ws + OFF_WB3S))[o] = h;
    }
}

// ===== conv1 stride-2 MFMA (4->32, split-bf16, fused epilogue) =====
__global__ __launch_bounds__(256) void mconv1_s2_kernel(
    const unsigned short* __restrict__ xcl,  // [b][z][y][x][8]
    const unsigned short* __restrict__ wb,   // [tap][n32][kc2][8]
    const float* __restrict__ bias, const float* __restrict__ mask,
    const float* __restrict__ zerow,
    float* __restrict__ t1, unsigned short* __restrict__ sqcl)
{
    constexpr int DIN = 64, DOUT = 32;
    constexpr int NTX = 4, NTY = 8;
    int r = blockIdx.x;
    int tx0 = (r % NTX) * 8; r /= NTX;
    int ty0 = (r % NTY) * 4; r /= NTY;
    int tz0 = (r % 8) * 4;   int b = r / 8;

    int tid = threadIdx.x;
    int lane = tid & 63, w = tid >> 6;
    int n = lane & 31, kc = lane >> 5;
    int oz = tz0 + w, oy = ty0 + (n >> 3), ox = tx0 + (n & 7);

    f32x16v acc;
#pragma unroll
    for (int i = 0; i < 16; ++i) acc[i] = 0.f;

#pragma unroll 1
    for (int kz = 0; kz < 5; ++kz) {
        int gz = 2 * oz + kz - 2;
        bool zok = (unsigned)gz < (unsigned)DIN;
#pragma unroll 1
        for (int ky = 0; ky < 5; ++ky) {
            int gy = 2 * oy + ky - 2;
            bool zyok = zok && ((unsigned)gy < (unsigned)DIN);
            long long rowbase = (((long long)(b * DIN + gz) * DIN + gy) * DIN) * 8;
#pragma unroll
            for (int kx = 0; kx < 5; ++kx) {
                int gx = 2 * ox + kx - 2;
                bool ok = zyok && ((unsigned)gx < (unsigned)DIN);
                const unsigned short* g = ok ? xcl + (rowbase + (long long)gx * 8)
                                             : (const unsigned short*)zerow;
                bf16x8v dfrag = *(const bf16x8v*)g;
                int tap = (kz * 5 + ky) * 5 + kx;
                const unsigned short* wp = wb + ((size_t)tap << 9) + n * 16 + kc * 8;
                bf16x8v wfrag = *(const bf16x8v*)wp;
                acc = __builtin_amdgcn_mfma_f32_32x32x16_bf16(wfrag, dfrag, acc, 0, 0, 0);
            }
        }
    }

    int sp = (oz * DOUT + oy) * DOUT + ox;
    float mval = mask[b * DOUT * DOUT * DOUT + sp];
#pragma unroll
    for (int q = 0; q < 4; ++q) {
        int co0 = 8 * q + 4 * kc;
        bf16x4v s4;
#pragma unroll
        for (int j = 0; j < 4; ++j) {
            int co = co0 + j;
            float v = (acc[4 * q + j] + bias[co]) * mval;
            t1[(size_t)(b * 32 + co) * 32768 + sp] = v;
            s4[j] = (short)f2bf(v * v);
        }
        *(bf16x4v*)(sqcl + ((size_t)(b * 32768 + sp)) * 32 + co0) = s4;
    }
}

// ===== fused GDN1 epilogue -> PLANAR y1 [pl4][b][vox][16] bf16 =====
// GDN1 mconv is CIG=1 -> single den partial.
__global__ __launch_bounds__(128) void gdn_cl1_kernel(const float* __restrict__ t,
        const float* __restrict__ pd, const float* __restrict__ beta,
        const float* __restrict__ scale, unsigned short* __restrict__ y1p) {
    constexpr size_t PLSZ = (size_t)Bn * 32768 * 16;   // shorts per plane
    int idx = blockIdx.x * 128 + threadIdx.x;   // < 65536 = Bn*32^3
    int sp = idx & 32767; int b = idx >> 15;
    float sc = scale[b];
    bf16x8v hi[4], lo[4];
#pragma unroll
    for (int g = 0; g < 4; ++g) {
#pragma unroll
        for (int j = 0; j < 8; ++j) {
            int ci = g * 8 + j;
            size_t p = (size_t)(b * 32 + ci) * 32768 + sp;
            float den = pd[p];
            float v = t[p] * rsqrtf(beta[ci] + den) * sc;
            unsigned short h = f2bf(v);
            hi[g][j] = (short)h;
            lo[g][j] = (short)f2bf(v - bf2f(h));
        }
    }
    size_t vo = ((size_t)b * 32768 + sp) * 16;
    *(bf16x8v*)(y1p + 0 * PLSZ + vo)     = hi[0];
    *(bf16x8v*)(y1p + 0 * PLSZ + vo + 8) = hi[1];
    *(bf16x8v*)(y1p + 1 * PLSZ + vo)     = hi[2];
    *(bf16x8v*)(y1p + 1 * PLSZ + vo + 8) = hi[3];
    *(bf16x8v*)(y1p + 2 * PLSZ + vo)     = lo[0];
    *(bf16x8v*)(y1p + 2 * PLSZ + vo + 8) = lo[1];
    *(bf16x8v*)(y1p + 3 * PLSZ + vo)     = lo[2];
    *(bf16x8v*)(y1p + 3 * PLSZ + vo + 8) = lo[3];
}

// ===== fused GDN2 epilogue + CL hi/lo/hi transform (64ch); sums 4 den partials =====
__global__ __launch_bounds__(128) void gdn_cl2_kernel(const float* __restrict__ t,
        const float* __restrict__ pd, const float* __restrict__ beta,
        const float* __restrict__ scale, unsigned short* __restrict__ yhl) {
    constexpr size_t NTOT = (size_t)Bn * 64 * 4096;
    int idx = blockIdx.x * 128 + threadIdx.x;   // < 8192 = Bn*16^3
    if (idx >= Bn * 4096) return;
    int sp = idx & 4095; int b = idx >> 12;
    float sc = scale[b];
    bf16x8v blk[24];
#pragma unroll
    for (int g = 0; g < 8; ++g) {
#pragma unroll
        for (int j = 0; j < 8; ++j) {
            int ci = g * 8 + j;
            size_t p = (size_t)(b * 64 + ci) * 4096 + sp;
            float den = pd[p] + pd[NTOT + p] + pd[2 * NTOT + p] + pd[3 * NTOT + p];
            float v = t[p] * rsqrtf(beta[ci] + den) * sc;
            unsigned short h = f2bf(v);
            blk[g][j] = (short)h;
            blk[8 + g][j] = (short)f2bf(v - bf2f(h));
            blk[16 + g][j] = (short)h;
        }
    }
    unsigned short* o = yhl + (size_t)idx * 192;
#pragma unroll
    for (int g = 0; g < 24; ++g) *(bf16x8v*)(o + g * 8) = blk[g];
}

// ===== planar-input stride-2 MFMA conv (conv2) =====
template<int COUTt, int DIN, int DOUT, int CIG, int ZSPL, int PLN>
__global__ __launch_bounds__(256) void mconv_s2p_kernel(
    const unsigned short* __restrict__ in,   // planar bf16
    const unsigned short* __restrict__ wb,   // [cs][nch][tap][n32][kc2][8]
    const float* __restrict__ zerow,
    float* __restrict__ pout)                // [zig*CIG+cs][b][co][vox] plain stores
{
    constexpr int NCH = COUTt / 32;
    constexpr int NTZ = DOUT / 4, NTY = DOUT / 4, NTX = (DOUT >= 8) ? DOUT / 8 : 1;
    constexpr int NT = NTZ * NTY * NTX * Bn;
    constexpr int VOX = DOUT * DOUT * DOUT;
    constexpr size_t PLSZ = (size_t)Bn * DIN * DIN * DIN * 16;

    int tile = blockIdx.x % NT; int rest = blockIdx.x / NT;
    int cs = rest % CIG; int zig = rest / CIG;
    int pl = cs % PLN;
    int r = tile;
    int tx0 = (r % NTX) * 8; r /= NTX;
    int ty0 = (r % NTY) * 4; r /= NTY;
    int tz0 = (r % NTZ) * 4; int b = r / NTZ;

    int tid = threadIdx.x;
    int lane = tid & 63, w = tid >> 6;
    int n = lane & 31, kc = lane >> 5;
    int oz = tz0 + w, oy = ty0 + (n >> 3), ox = tx0 + (n & 7);

    const unsigned short* inp = in + (size_t)pl * PLSZ;

    f32x16v acc[NCH];
#pragma unroll
    for (int c = 0; c < NCH; ++c)
#pragma unroll
        for (int i = 0; i < 16; ++i) acc[c][i] = 0.f;

    int kzlo, kzhi;
    if (ZSPL == 5)      { kzlo = zig;     kzhi = zig + 1; }
    else if (ZSPL == 3) { kzlo = 2 * zig; kzhi = (2 * zig + 2 < 5) ? 2 * zig + 2 : 5; }
    else                { kzlo = 0;       kzhi = 5; }
#pragma unroll 1
    for (int kz = kzlo; kz < kzhi; ++kz) {
        int gz = 2 * oz + kz - 2;
        bool zok = (unsigned)gz < (unsigned)DIN;
#pragma unroll 1
        for (int ky = 0; ky < 5; ++ky) {
            int gy = 2 * oy + ky - 2;
            bool zyok = zok && ((unsigned)gy < (unsigned)DIN);
            long long rowbase = (((long long)(b * DIN + gz) * DIN + gy) * DIN) * 16 + kc * 8;
#pragma unroll
            for (int kx = 0; kx < 5; ++kx) {
                int gx = 2 * ox + kx - 2;
                bool ok = zyok && ((unsigned)gx < (unsigned)DIN);
                const unsigned short* g = ok ? inp + (rowbase + (long long)gx * 16)
                                             : (const unsigned short*)zerow;
                bf16x8v dfrag = *(const bf16x8v*)g;
                int tap = (kz * 5 + ky) * 5 + kx;
#pragma unroll
                for (int c = 0; c < NCH; ++c) {
                    const unsigned short* wp =
                        wb + (((size_t)(cs * NCH + c) * 125 + tap) << 9) + n * 16 + kc * 8;
                    bf16x8v wfrag = *(const bf16x8v*)wp;
                    acc[c] = __builtin_amdgcn_mfma_f32_32x32x16_bf16(wfrag, dfrag, acc[c], 0, 0, 0);
                }
            }
        }
    }

    int sp = (oz * DOUT + oy) * DOUT + ox;
#pragma unroll
    for (int c = 0; c < NCH; ++c) {
#pragma unroll
        for (int rr = 0; rr < 16; ++rr) {
            int co = c * 32 + (rr & 3) + 8 * (rr >> 2) + 4 * kc;
            pout[((size_t)((zig * CIG + cs) * Bn + b) * COUTt + co) * VOX + sp] = acc[c][rr];
        }
    }
}

// ===== stride-2 MFMA conv, channel-last input (conv3) =====
template<int CINe, int COUTt, int DIN, int DOUT, int CIG, int ZSPL>
__global__ __launch_bounds__(256) void mconv_s2_kernel(
    const unsigned short* __restrict__ in,   // CL bf16 [b][z][y][x][CINe]
    const unsigned short* __restrict__ wb,   // [cs][nch][tap][n32][kc2][8]
    const float* __restrict__ zerow,
    float* __restrict__ pout)                // [zig*CIG+cs][b][co][vox] plain stores
{
    constexpr int NCH = COUTt / 32;
    constexpr int NTZ = DOUT / 4, NTY = DOUT / 4, NTX = (DOUT >= 8) ? DOUT / 8 : 1;
    constexpr int NT = NTZ * NTY * NTX * Bn;
    constexpr int VOX = DOUT * DOUT * DOUT;

    int tile = blockIdx.x % NT; int rest = blockIdx.x / NT;
    int cs = rest % CIG; int zig = rest / CIG;
    int r = tile;
    int tx0 = (r % NTX) * 8; r /= NTX;
    int ty0 = (r % NTY) * 4; r /= NTY;
    int tz0 = (r % NTZ) * 4; int b = r / NTZ;

    int tid = threadIdx.x;
    int lane = tid & 63, w = tid >> 6;
    int n = lane & 31, kc = lane >> 5;
    int oz = tz0 + w, oy = ty0 + (n >> 3), ox = tx0 + (n & 7);

    f32x16v acc[NCH];
#pragma unroll
    for (int c = 0; c < NCH; ++c)
#pragma unroll
        for (int i = 0; i < 16; ++i) acc[c][i] = 0.f;

    int kzlo, kzhi;
    if (ZSPL == 5)      { kzlo = zig;     kzhi = zig + 1; }
    else if (ZSPL == 3) { kzlo = 2 * zig; kzhi = (2 * zig + 2 < 5) ? 2 * zig + 2 : 5; }
    else                { kzlo = 0;       kzhi = 5; }
#pragma unroll 1
    for (int kz = kzlo; kz < kzhi; ++kz) {
        int gz = 2 * oz + kz - 2;
        bool zok = (unsigned)gz < (unsigned)DIN;
#pragma unroll 1
        for (int ky = 0; ky < 5; ++ky) {
            int gy = 2 * oy + ky - 2;
            bool zyok = zok && ((unsigned)gy < (unsigned)DIN);
            long long rowbase = (((long long)(b * DIN + gz) * DIN + gy) * DIN) * CINe
                                + cs * 16 + kc * 8;
#pragma unroll
            for (int kx = 0; kx < 5; ++kx) {
                int gx = 2 * ox + kx - 2;
                bool ok = zyok && ((unsigned)gx < (unsigned)DIN);
                const unsigned short* g = ok ? in + (rowbase + (long long)gx * CINe)
                                             : (const unsigned short*)zerow;
                bf16x8v dfrag = *(const bf16x8v*)g;
                int tap = (kz * 5 + ky) * 5 + kx;
#pragma unroll
                for (int c = 0; c < NCH; ++c) {
                    const unsigned short* wp =
                        wb + (((size_t)(cs * NCH + c) * 125 + tap) << 9) + n * 16 + kc * 8;
                    bf16x8v wfrag = *(const bf16x8v*)wp;
                    acc[c] = __builtin_amdgcn_mfma_f32_32x32x16_bf16(wfrag, dfrag, acc[c], 0, 0, 0);
                }
            }
        }
    }

    int sp = (oz * DOUT + oy) * DOUT + ox;
#pragma unroll
    for (int c = 0; c < NCH; ++c) {
#pragma unroll
        for (int rr = 0; rr < 16; ++rr) {
            int co = c * 32 + (rr & 3) + 8 * (rr >> 2) + 4 * kc;
            pout[((size_t)((zig * CIG + cs) * Bn + b) * COUTt + co) * VOX + sp] = acc[c][rr];
        }
    }
}

// reduce split-K partials + bias + mask -> t fp32 NCDHW, and sq CL bf16
template<int CS, int COUTt, int VOX>
__global__ __launch_bounds__(256) void red_epi_kernel(const float* __restrict__ P,
        const float* __restrict__ bias, const float* __restrict__ mask,
        float* __restrict__ buf, unsigned short* __restrict__ sqcl) {
    constexpr int NTOT = Bn * COUTt * VOX;
    int idx = blockIdx.x * 256 + threadIdx.x;
    if (idx >= NTOT) return;
    int sp = idx % VOX;
    int co = (idx / VOX) % COUTt;
    int b = idx / (VOX * COUTt);
    float s = 0.f;
#pragma unroll
    for (int k = 0; k < CS; ++k) s += P[(size_t)k * NTOT + idx];
    float v = (s + bias[co]) * mask[b * VOX + sp];
    buf[idx] = v;
    sqcl[((size_t)b * VOX + sp) * COUTt + co] = f2bf(v * v);
}

// ===== MFMA conv (stride-1): GDN denominators + conv4 =====
// Plain-store partials [g][b][co][vox]. R18: csl-major LDS layout —
// each cs-group is a separate contiguous plane [csl][vox][16ch], so the
// per-csl dfrag read keeps the 32B voxel stride (R12's interleaved [vox][32ch]
// layout doubled the stride -> 6.1M bank-conflict cycles, +12us on GDN1).
template<int CINt, int COUTt, int Dd, int TZ, int YB, int CIG, int ZSPL>
__global__ __launch_bounds__(256) void mconv_kernel(
    const unsigned short* __restrict__ in,   // CL bf16 [b][z][y][x][CINt]
    const unsigned short* __restrict__ wb,
    const float* __restrict__ zerow,
    float* __restrict__ pout)                // [g][b][co][vox] plain stores
{
    constexpr int NCH = COUTt / 32;
    constexpr int CSPB = (CINt / 16) / CIG;    // cs-groups per block
    constexpr int CHS = CSPB * 16;             // shorts per voxel in global CL
    constexpr int LZ = TZ + 4, LYH = YB * 4 + 4, LXH = 12;
    constexpr int HV = LZ * LYH * LXH;
    constexpr int UNP = 2 * HV;                // 16B units per csl plane
    constexpr int UN = CSPB * UNP;             // total 16B units
    constexpr int NLOAD = (UN + 255) / 256;
    constexpr int NTZ = Dd / TZ, NTY = Dd / (YB * 4), NTX = Dd / 8;
    constexpr int NT = NTZ * NTY * NTX * Bn;
    constexpr int VOX = Dd * Dd * Dd;
    __shared__ unsigned short lds[NLOAD * 256 * 8];

    int bid = blockIdx.x;
    int tile = bid % NT; int rest = bid / NT;
    int cs = rest % CIG; int zig = rest / CIG;
    int r = tile;
    int tx0 = (r % NTX) * 8; r /= NTX;
    int ty0 = (r % NTY) * (YB * 4); r /= NTY;
    int tz0 = (r % NTZ) * TZ; int b = r / NTZ;

    int tid = threadIdx.x;
    int iz0 = tz0 - 2, iy0 = ty0 - 2, ix0 = tx0 - 2;
#pragma unroll
    for (int k = 0; k < NLOAD; ++k) {
        int u = tid + k * 256;
        int csl = u / UNP;                     // plane index (csl-major)
        int rem = u % UNP;
        int v = rem >> 1, half = rem & 1;
        int lx = v % LXH; int t = v / LXH;
        int ly = t % LYH, lz = t / LYH;
        int gz = iz0 + lz, gy = iy0 + ly, gx = ix0 + lx;
        bool valid = (csl < CSPB) && (v < HV) &&
                     (unsigned)gz < (unsigned)Dd && (unsigned)gy < (unsigned)Dd &&
                     (unsigned)gx < (unsigned)Dd;
        const unsigned short* g = valid
            ? in + ((((size_t)b * Dd + gz) * Dd + gy) * Dd + gx) * CINt
                 + cs * CHS + csl * 16 + half * 8
            : (const unsigned short*)zerow;
        async_copy16((const float*)g, (float*)&lds[(size_t)u * 8]);
    }
    __syncthreads();

    int lane = tid & 63, w = tid >> 6;
    int zz = (YB == 1) ? w : (w >> 1);
    int yb = (YB == 1) ? 0 : (w & 1);
    int n = lane & 31, kc = lane >> 5;
    int vy = yb * 4 + (n >> 3), vx = n & 7;

    f32x16v acc[NCH];
#pragma unroll
    for (int c = 0; c < NCH; ++c)
#pragma unroll
        for (int i = 0; i < 16; ++i) acc[c][i] = 0.f;

    int kzlo = (ZSPL == 5) ? zig : 0;
    int kzhi = (ZSPL == 5) ? zig + 1 : 5;
#pragma unroll 1
    for (int csl = 0; csl < CSPB; ++csl) {
        int csabs = cs * CSPB + csl;
        const unsigned short* lplane = &lds[(size_t)csl * HV * 16];
#pragma unroll 1
        for (int kz = kzlo; kz < kzhi; ++kz) {
#pragma unroll 1
            for (int ky = 0; ky < 5; ++ky) {
                int hvrow = ((zz + kz) * LYH + (vy + ky)) * LXH + vx;
#pragma unroll
                for (int kx = 0; kx < 5; ++kx) {
                    bf16x8v dfrag = *(const bf16x8v*)&lplane[(size_t)(hvrow + kx) * 16 + kc * 8];
                    int tap = (kz * 5 + ky) * 5 + kx;
#pragma unroll
                    for (int c = 0; c < NCH; ++c) {
                        const unsigned short* wp =
                            wb + (((size_t)(csabs * NCH + c) * 125 + tap) << 9) + n * 16 + kc * 8;
                        bf16x8v wfrag = *(const bf16x8v*)wp;
                        acc[c] = __builtin_amdgcn_mfma_f32_32x32x16_bf16(wfrag, dfrag, acc[c], 0, 0, 0);
                    }
                }
            }
        }
    }

    int g = rest;                            // zig*CIG + cs
    int sp = ((tz0 + zz) * Dd + (ty0 + vy)) * Dd + (tx0 + vx);
#pragma unroll
    for (int c = 0; c < NCH; ++c) {
#pragma unroll
        for (int rr = 0; rr < 16; ++rr) {
            int co = c * 32 + (rr & 3) + 8 * (rr >> 2) + 4 * kc;
            pout[((size_t)(g * Bn + b) * COUTt + co) * VOX + sp] = acc[c][rr];
        }
    }
}

// GDN3 epilogue: sum G den partials, rsqrt, scale -> y3 CL bf16
template<int G, int COUTt, int DOUT>
__global__ __launch_bounds__(256) void gdn_red_cl_kernel(const float* __restrict__ t,
        const float* __restrict__ pd, const float* __restrict__ beta,
        const float* __restrict__ scale, unsigned short* __restrict__ ycl) {
    constexpr int VOX = DOUT * DOUT * DOUT;
    constexpr int NTOT = Bn * COUTt * VOX;
    int idx = blockIdx.x * 256 + threadIdx.x;
    if (idx >= NTOT) return;
    int sp = idx % VOX;
    int co = (idx / VOX) % COUTt;
    int b = idx / (VOX * COUTt);
    float den = 0.f;
#pragma unroll
    for (int k = 0; k < G; ++k) den += pd[(size_t)k * NTOT + idx];
    float v = t[idx] * rsqrtf(beta[co] + den) * scale[b];
    ycl[((size_t)b * VOX + sp) * COUTt + co] = f2bf(v);
}

// conv4 epilogue: sum G conv partials + bias + mask -> out fp32
template<int G, int COUTt, int DOUT>
__global__ __launch_bounds__(256) void conv_red_kernel(const float* __restrict__ pc,
        const float* __restrict__ bias, const float* __restrict__ mask,
        float* __restrict__ outx) {
    constexpr int VOX = DOUT * DOUT * DOUT;
    constexpr int NTOT = Bn * COUTt * VOX;
    int idx = blockIdx.x * 256 + threadIdx.x;
    if (idx >= NTOT) return;
    int sp = idx % VOX;
    int co = (idx / VOX) % COUTt;
    int b = idx / (VOX * COUTt);
    float s = 0.f;
#pragma unroll
    for (int k = 0; k < G; ++k) s += pc[(size_t)k * NTOT + idx];
    outx[idx] = (s + bias[co]) * mask[b * VOX + sp];
}

extern "C" void kernel_launch(void* const* d_in, const int* in_sizes, int n_in,
                              void* d_out, int out_size, void* d_ws, size_t ws_size,
                              hipStream_t stream) {
    const float* x_feat = (const float*)d_in[0];
    const float* QF     = (const float*)d_in[2];
    const float* w1 = (const float*)d_in[3];  const float* b1 = (const float*)d_in[4];
    const float* w2 = (const float*)d_in[5];  const float* b2 = (const float*)d_in[6];
    const float* w3 = (const float*)d_in[7];  const float* b3 = (const float*)d_in[8];
    const float* w4 = (const float*)d_in[9];  const float* b4 = (const float*)d_in[10];
    const float* beta1 = (const float*)d_in[11]; const float* gamma1 = (const float*)d_in[12];
    const float* beta2 = (const float*)d_in[13]; const float* gamma2 = (const float*)d_in[14];
    const float* beta3 = (const float*)d_in[15]; const float* gamma3 = (const float*)d_in[16];

    float* out = (float*)d_out;
    float* ws = (float*)d_ws;
    float* cnt   = ws + OFF_CNT;
    float* zerow = ws + OFF_ZERO;
    float* scale = ws + OFF_SCALE;
    float* m1 = ws + OFF_M1;  float* m2 = ws + OFF_M2;  float* m3 = ws + OFF_M3;
    float* t1 = ws + OFF_T1;
    float* t2 = ws + OFF_T2;
    float* t3 = ws + OFF_T3;
    float* pu = ws + OFF_PU;            // union partial buffer (all split-K producers)
    unsigned short* sq1 = (unsigned short*)(ws + OFF_SQ1);
    unsigned short* sq2 = (unsigned short*)(ws + OFF_SQ2);
    unsigned short* sq3 = (unsigned short*)(ws + OFF_SQ3);
    unsigned short* y3c = (unsigned short*)(ws + OFF_Y3C);
    unsigned short* y1p = (unsigned short*)(ws + OFF_Y1P);
    unsigned short* y2hl = (unsigned short*)(ws + OFF_Y2HL);
    unsigned short* xcl = (unsigned short*)(ws + OFF_Y1);
    unsigned short* wb1 = (unsigned short*)(ws + OFF_WB1);
    unsigned short* wb2 = (unsigned short*)(ws + OFF_WB2);
    unsigned short* wb3 = (unsigned short*)(ws + OFF_WB3);
    unsigned short* wb4 = (unsigned short*)(ws + OFF_WB4);
    unsigned short* wb1s = (unsigned short*)(ws + OFF_WB1S);
    unsigned short* wb2s = (unsigned short*)(ws + OFF_WB2S);
    unsigned short* wb3s = (unsigned short*)(ws + OFF_WB3S);

    // Only cnt (pool accumulators) + zerow need zeroing; all partials are
    // plain-store-then-reduce, and out is fully overwritten.
    hipMemsetAsync(ws, 0, 16 * sizeof(float), stream);

    qmean_kernel<<<4, 256, 0, stream>>>(QF, out + OUT_Q, scale);
    // fused mask + xcl (single x_feat pass) ; fused pool m2+m3 ; k write
    maskxcl_kernel<<<256, 256, 0, stream>>>(x_feat, m1, cnt + 0, xcl);
    pool23_kernel<<<4, 256, 0, stream>>>(m1, m2, m3, cnt);
    writek_kernel<<<1, 64, 0, stream>>>(cnt, out + OUT_K);

    // all weight transforms in one launch
    wall_kernel<<<(WALL_N + 255) / 256, 256, 0, stream>>>(
        gamma1, gamma2, gamma3, w4, w1, w2, w3, ws);

    // Stage 1: conv1 MFMA s2 split-bf16 (K=16, fused epi -> t1 + sq1CL) ;
    //          GDN1 MFMA CIG=1 (CSPB=2 csl-major planes, 1 den partial) ;
    //          gdn_cl1 -> PLANAR y1p
    mconv1_s2_kernel<<<512, 256, 0, stream>>>(xcl, wb1s, b1, m1, zerow, t1, sq1);
    mconv_kernel<32, 32, 32, 4, 1, 1, 1>
        <<<512, 256, 0, stream>>>(sq1, wb1, zerow, pu);
    gdn_cl1_kernel<<<512, 128, 0, stream>>>(t1, pu, beta1, scale, y1p);

    // Stage 2: conv2 MFMA s2 split-bf16, PLANAR gather (cs x6 -> pl=cs&3,
    //          kz-pairs x3, 1152 blocks) ; reduce 18 + epi ; GDN2 MFMA -> 4
    //          partials ; gdn_cl2 -> y2hl
    mconv_s2p_kernel<64, 32, 16, 6, 3, 4>
        <<<64 * 6 * 3, 256, 0, stream>>>(y1p, wb2s, zerow, pu);
    red_epi_kernel<18, 64, 4096><<<2048, 256, 0, stream>>>(pu, b2, m2, t2, sq2);
    mconv_kernel<64, 64, 16, 4, 1, 4, 1>
        <<<256, 256, 0, stream>>>(sq2, wb2, zerow, pu);
    gdn_cl2_kernel<<<64, 128, 0, stream>>>(t2, pu, beta2, scale, y2hl);

    // Stage 3: conv3 MFMA s2 split-bf16 (cs x12, kz x5) -> pu ; reduce 60 + epi ;
    //          GDN3 MFMA -> 30 partials (pu) ; gdn_red_cl sums -> y3 CL bf16
    mconv_s2_kernel<192, 96, 16, 8, 12, 5>
        <<<8 * 12 * 5, 256, 0, stream>>>(y2hl, wb3s, zerow, pu);
    red_epi_kernel<60, 96, 512><<<384, 256, 0, stream>>>(pu, b3, m3, t3, sq3);
    mconv_kernel<96, 96, 8, 2, 2, 6, 5>
        <<<240, 256, 0, stream>>>(sq3, wb3, zerow, pu);
    gdn_red_cl_kernel<30, 96, 8><<<384, 256, 0, stream>>>(t3, pu, beta3, scale, y3c);

    // Stage 4: conv4 MFMA (96->128, s1) -> 30 partials (pu) ;
    //          conv_red sums + bias + mask -> out
    mconv_kernel<96, 128, 8, 2, 2, 6, 5>
        <<<240, 256, 0, stream>>>(y3c, wb4, zerow, pu);
    conv_red_kernel<30, 128, 8><<<512, 256, 0, stream>>>(pu, b4, m3, out + OUT_X);
}

// Round 14
// 383.006 us; speedup vs baseline: 1.0677x; 1.0586x over previous
//
#include <hip/hip_runtime.h>
#include <math.h>

// Problem constants
constexpr int Bn  = 2;
constexpr int CIN = 4;
constexpr int MQn = 1024;
constexpr int D0 = 64, D1 = 32, D2 = 16, D3 = 8;

// Output layout (floats): x [2,128,8,8,8] = 131072, q [1,2,2] = 4, k [3,2] = 6
constexpr int OUT_X = 0;
constexpr int OUT_Q = 131072;
constexpr int OUT_K = 131076;

// Workspace layout (floats). Only cnt+zerow (16 fl) need zeroing.
constexpr size_t OFF_CNT   = 0;
constexpr size_t OFF_ZERO  = 8;                    // 32B zero block for DMA padding
constexpr size_t OFF_D1    = 16;                   // (dead accumulator slots, kept as spacing)
constexpr size_t OFF_T2    = OFF_D1 + 2097152;     // t2 fp32 2*64*16^3
constexpr size_t OFF_D2    = OFF_T2 + 524288;
constexpr size_t OFF_T3    = OFF_D2 + 524288;      // t3 fp32 2*96*8^3
constexpr size_t OFF_D3    = OFF_T3 + 98304;
constexpr size_t ZERO_END  = OFF_D3 + 98304;
// non-zeroed region
constexpr size_t OFF_SCALE = 3342360;
constexpr size_t OFF_M1    = 3342368;              // 2*32^3
constexpr size_t OFF_M2    = OFF_M1 + 65536;
constexpr size_t OFF_M3    = OFF_M2 + 8192;
constexpr size_t OFF_T1    = OFF_M3 + 1024;        // 2*32*32^3
constexpr size_t OFF_Y1    = OFF_T1 + 2097152;     // xcl [b][64^3][8] bf16 hi4|lo4
constexpr size_t OFF_Y2    = OFF_Y1 + 2097152;     // (unused, kept for layout)
// channel-last bf16 buffers (sizes in floats = shorts/2)
constexpr size_t OFF_SQ1   = OFF_Y2 + 524288;      // 2*32^3*32 sh = 1048576 fl
constexpr size_t OFF_SQ2   = OFF_SQ1 + 1048576;    // 2*16^3*64 sh = 262144 fl
constexpr size_t OFF_SQ3   = OFF_SQ2 + 262144;     // 2*8^3*96 sh = 49152 fl
constexpr size_t OFF_Y3C   = OFF_SQ3 + 49152;      // 2*8^3*96 sh = 49152 fl
// (dead fp32 transposed-weight slots kept as spacing)
constexpr size_t OFF_W1T   = OFF_Y3C + 49152;      // 16000
constexpr size_t OFF_W2T   = OFF_W1T + 16000;      // 256000
constexpr size_t OFF_W3T   = OFF_W2T + 256000;     // 768000
// bf16 MFMA weights [cs][nch][tap][n32][kc2][8]
constexpr size_t OFF_WB1   = OFF_W3T + 768000;     // 128000 sh = 64000 fl
constexpr size_t OFF_WB2   = OFF_WB1 + 64000;      // 512000 sh = 256000 fl
constexpr size_t OFF_WB3   = OFF_WB2 + 256000;     // 1152000 sh = 576000 fl
constexpr size_t OFF_WB4   = OFF_WB3 + 576000;     // 1536000 sh = 768000 fl
// UNION partial buffer, time-shared by ALL split-K producers (max = conv2 18 gr)
constexpr size_t OFF_PU    = 12248736;             // 9437184 fl
// y1 planar [pl4][b][32^3 vox][16ch] bf16 (pl = cs&3; cs4/5 alias 0/1)
constexpr size_t OFF_Y1P   = OFF_PU + 9437184;     // 4*2*32768*16 sh = 2097152 fl
constexpr size_t OFF_WB2S  = OFF_Y1P + 3145728;    // w2 eff bf16 [cs6][nch2][tap][512]
constexpr size_t OFF_WB1S  = OFF_WB2S + 384000;    // conv1 [tap][n32][kc2][8]: 64000 sh
constexpr size_t OFF_WB3S  = OFF_WB1S + 32000;     // w3 eff bf16 [cs12][nch3][tap][512]: 2304000 sh
constexpr size_t OFF_Y2HL  = OFF_WB3S + 1152000;   // y2 CL [b][vox][192] bf16: 1572864 sh
// end = 27186080 floats (~109 MB)

typedef float v4f __attribute__((ext_vector_type(4)));
typedef __attribute__((ext_vector_type(8)))  short bf16x8v;
typedef __attribute__((ext_vector_type(4)))  short bf16x4v;
typedef __attribute__((ext_vector_type(16))) float f32x16v;

__device__ __forceinline__ void async_copy16(const float* g, float* l) {
    __builtin_amdgcn_global_load_lds(
        (const __attribute__((address_space(1))) void*)g,
        (__attribute__((address_space(3))) void*)l, 16, 0, 0);
}
__device__ __forceinline__ unsigned short f2bf(float f) {
    unsigned u = __float_as_uint(f);
    return (unsigned short)((u + 0x7FFFu + ((u >> 16) & 1u)) >> 16);
}
__device__ __forceinline__ float bf2f(unsigned short h) {
    return __uint_as_float((unsigned)h << 16);
}

__global__ void qmean_kernel(const float* __restrict__ QF, float* __restrict__ out_q,
                             float* __restrict__ scale) {
    int b = blockIdx.x >> 1, c = blockIdx.x & 1;
    float s = 0.f;
    for (int m = threadIdx.x; m < MQn; m += blockDim.x)
        s += QF[(b * MQn + m) * 2 + c];
    __shared__ float sh[256];
    sh[threadIdx.x] = s;
    __syncthreads();
    for (int st = 128; st > 0; st >>= 1) {
        if (threadIdx.x < st) sh[threadIdx.x] += sh[threadIdx.x + st];
        __syncthreads();
    }
    if (threadIdx.x == 0) {
        float mean = sh[0] / (float)MQn;
        out_q[b * 2 + c] = mean;
        if (c == 0) scale[b] = mean;
    }
}

// ===== fused mask_pool1 + xcl: single pass over x_feat =====
__global__ __launch_bounds__(256) void maskxcl_kernel(const float* __restrict__ xf,
        float* __restrict__ m1, float* __restrict__ c0,
        unsigned short* __restrict__ xcl) {
    int idx = blockIdx.x * 256 + threadIdx.x;   // 0..65535
    int b = idx >> 15;
    int v = idx & 32767;
    int oz = v >> 10, oy = (v >> 5) & 31, ox = v & 31;
    float cnt = 0.f, mx = 0.f;
    for (int dz = 0; dz < 2; ++dz)
        for (int dy = 0; dy < 2; ++dy)
            for (int dx = 0; dx < 2; ++dx) {
                int z = 2 * oz + dz, y = 2 * oy + dy, x = 2 * ox + dx;
                size_t s = ((size_t)z * D0 + y) * D0 + x;
                size_t base = (size_t)b * CIN * 262144 + s;
                bool occ = false;
                bf16x8v o;
#pragma unroll
                for (int c = 0; c < 4; ++c) {
                    float f = xf[base + (size_t)c * 262144];
                    occ = occ || (f != 0.f);
                    unsigned short h = f2bf(f);
                    o[c] = (short)h;
                    o[4 + c] = (short)f2bf(f - bf2f(h));
                }
                *(bf16x8v*)(xcl + ((size_t)b * 262144 + s) * 8) = o;
                if (occ) { cnt += 1.f; mx = 1.f; }
            }
    m1[idx] = mx;
    __shared__ float sh[256];
    sh[threadIdx.x] = cnt;
    __syncthreads();
    for (int st = 128; st > 0; st >>= 1) {
        if (threadIdx.x < st) sh[threadIdx.x] += sh[threadIdx.x + st];
        __syncthreads();
    }
    if (threadIdx.x == 0) atomicAdd(&c0[b], sh[0]);
}

// ===== fused pool m1->m2->m3 + c1/c2 accumulation =====
__global__ __launch_bounds__(256) void pool23_kernel(const float* __restrict__ m1,
        float* __restrict__ m2, float* __restrict__ m3, float* __restrict__ cnt) {
    int idx = blockIdx.x * 256 + threadIdx.x;   // 0..1023 (2*8^3)
    int b = idx >> 9;
    int v = idx & 511;
    int oz = v >> 6, oy = (v >> 3) & 7, ox = v & 7;
    float s1 = 0.f, s2 = 0.f, mx3 = 0.f;
#pragma unroll
    for (int a = 0; a < 2; ++a)
#pragma unroll
        for (int bb = 0; bb < 2; ++bb)
#pragma unroll
            for (int cc = 0; cc < 2; ++cc) {
                float mx2 = 0.f;
#pragma unroll
                for (int dz = 0; dz < 2; ++dz)
#pragma unroll
                    for (int dy = 0; dy < 2; ++dy)
#pragma unroll
                        for (int dx = 0; dx < 2; ++dx) {
                            int z = 4 * oz + 2 * a + dz, y = 4 * oy + 2 * bb + dy,
                                x = 4 * ox + 2 * cc + dx;
                            float val = m1[(((size_t)b * 32 + z) * 32 + y) * 32 + x];
                            s1 += val;
                            mx2 = fmaxf(mx2, val);
                        }
                m2[(((size_t)b * 16 + 2 * oz + a) * 16 + 2 * oy + bb) * 16 + 2 * ox + cc] = mx2;
                s2 += mx2;
                mx3 = fmaxf(mx3, mx2);
            }
    m3[idx] = mx3;
    __shared__ float sh[256][2];
    sh[threadIdx.x][0] = s1;
    sh[threadIdx.x][1] = s2;
    __syncthreads();
    for (int st = 128; st > 0; st >>= 1) {
        if (threadIdx.x < st) {
            sh[threadIdx.x][0] += sh[threadIdx.x + st][0];
            sh[threadIdx.x][1] += sh[threadIdx.x + st][1];
        }
        __syncthreads();
    }
    if (threadIdx.x == 0) {
        atomicAdd(&cnt[2 + b], sh[0][0]);
        atomicAdd(&cnt[4 + b], sh[0][1]);
    }
}

__global__ void writek_kernel(const float* __restrict__ cnt, float* __restrict__ outk) {
    int i = threadIdx.x;
    if (i < 6) {
        int row = i >> 1, b = i & 1;
        float v = (row == 0) ? cnt[4 + b] : (row == 1 ? cnt[2 + b] : cnt[b]);
        outk[i] = v;
    }
}

// ===== ALL weight transforms in one kernel =====
constexpr int MS1 = 0,        ME1 = 128000;   // gamma1 NCH1 CIN32
constexpr int MS2 = 128000,   ME2 = 640000;   // gamma2 NCH2 CIN64
constexpr int MS3 = 640000,   ME3 = 1792000;  // gamma3 NCH3 CIN96
constexpr int MS4 = 1792000,  ME4 = 3328000;  // w4     NCH4 CIN96
constexpr int W1S_N = 64000;    // 125tap * 512
constexpr int W2S_N = 768000;   // 6cs * 2nch * 125tap * 512
constexpr int W3S_N = 2304000;  // 12cs * 3nch * 125tap * 512
constexpr int WALL2 = ME4 + W1S_N;
constexpr int WALL3 = WALL2 + W2S_N;
constexpr int WALL_N = WALL3 + W3S_N;        // 6464000
__global__ __launch_bounds__(256) void wall_kernel(
        const float* __restrict__ g1, const float* __restrict__ g2,
        const float* __restrict__ g3, const float* __restrict__ w4,
        const float* __restrict__ w1, const float* __restrict__ w2,
        const float* __restrict__ w3, float* __restrict__ ws) {
    int idx = blockIdx.x * 256 + threadIdx.x;
    if (idx >= WALL_N) return;
    if (idx < ME4) {
        const float* src; unsigned short* dst; int nchn, cin, o;
        if (idx < ME1)      { src = g1; dst = (unsigned short*)(ws + OFF_WB1); nchn = 1; cin = 32; o = idx - MS1; }
        else if (idx < ME2) { src = g2; dst = (unsigned short*)(ws + OFF_WB2); nchn = 2; cin = 64; o = idx - MS2; }
        else if (idx < ME3) { src = g3; dst = (unsigned short*)(ws + OFF_WB3); nchn = 3; cin = 96; o = idx - MS3; }
        else                { src = w4; dst = (unsigned short*)(ws + OFF_WB4); nchn = 4; cin = 96; o = idx - MS4; }
        int j  = o & 7;
        int kc = (o >> 3) & 1;
        int n  = (o >> 4) & 31;
        int q  = o >> 9;
        int tap = q % 125;
        int q2  = q / 125;
        int nch = q2 % nchn;
        int cs  = q2 / nchn;
        int co = nch * 32 + n;
        int ci = cs * 16 + kc * 8 + j;
        dst[o] = f2bf(src[((size_t)co * cin + ci) * 125 + tap]);
    } else if (idx < WALL2) {
        int o = idx - ME4;
        int j = o & 7; int kc = (o >> 3) & 1; int n = (o >> 4) & 31; int tap = o >> 9;
        int ci = j & 3;
        unsigned short h;
        float wv = w1[((size_t)n * 4 + ci) * 125 + tap];
        unsigned short hi = f2bf(wv);
        if (kc == 0)       h = hi;
        else if (j < 4)    h = f2bf(wv - bf2f(hi));
        else               h = 0;
        ((unsigned short*)(ws + OFF_WB1S))[o] = h;
    } else if (idx < WALL3) {
        int o = idx - WALL2;
        int j = o & 7; int kc = (o >> 3) & 1; int n = (o >> 4) & 31; int q = o >> 9;
        int tap = q % 125; int q2 = q / 125; int c = q2 & 1; int cs = q2 >> 1;
        int co = c * 32 + n;
        int e = cs * 16 + kc * 8 + j;
        int ci = e & 31;
        float wv = w2[((size_t)co * 32 + ci) * 125 + tap];
        unsigned short h = f2bf(wv);
        if (e >= 64) h = f2bf(wv - bf2f(h));
        ((unsigned short*)(ws + OFF_WB2S))[o] = h;
    } else {
        int o = idx - WALL3;
        int j = o & 7; int kc = (o >> 3) & 1; int n = (o >> 4) & 31; int q = o >> 9;
        int tap = q % 125; int q2 = q / 125; int nch = q2 % 3; int cs = q2 / 3;
        int co = nch * 32 + n;
        int e = cs * 16 + kc * 8 + j;
        int ci = e & 63;
        float wv = w3[((size_t)co * 64 + ci) * 125 + tap];
        unsigned short h = f2bf(wv);
        if (e >= 128) h = f2bf(wv - bf2f(h));
        ((unsigned short*)(ws + OFF_WB3S))[o] = h;
    }
}

// ===== conv1 stride-2 MFMA (4->32, split-bf16, fused epilogue) =====
__global__ __launch_bounds__(256) void mconv1_s2_kernel(
    const unsigned short* __restrict__ xcl,  // [b][z][y][x][8]
    const unsigned short* __restrict__ wb,   // [tap][n32][kc2][8]
    const float* __restrict__ bias, const float* __restrict__ mask,
    const float* __restrict__ zerow,
    float* __restrict__ t1, unsigned short* __restrict__ sqcl)
{
    constexpr int DIN = 64, DOUT = 32;
    constexpr int NTX = 4, NTY = 8;
    int r = blockIdx.x;
    int tx0 = (r % NTX) * 8; r /= NTX;
    int ty0 = (r % NTY) * 4; r /= NTY;
    int tz0 = (r % 8) * 4;   int b = r / 8;

    int tid = threadIdx.x;
    int lane = tid & 63, w = tid >> 6;
    int n = lane & 31, kc = lane >> 5;
    int oz = tz0 + w, oy = ty0 + (n >> 3), ox = tx0 + (n & 7);

    f32x16v acc;
#pragma unroll
    for (int i = 0; i < 16; ++i) acc[i] = 0.f;

#pragma unroll 1
    for (int kz = 0; kz < 5; ++kz) {
        int gz = 2 * oz + kz - 2;
        bool zok = (unsigned)gz < (unsigned)DIN;
#pragma unroll 1
        for (int ky = 0; ky < 5; ++ky) {
            int gy = 2 * oy + ky - 2;
            bool zyok = zok && ((unsigned)gy < (unsigned)DIN);
            long long rowbase = (((long long)(b * DIN + gz) * DIN + gy) * DIN) * 8;
#pragma unroll
            for (int kx = 0; kx < 5; ++kx) {
                int gx = 2 * ox + kx - 2;
                bool ok = zyok && ((unsigned)gx < (unsigned)DIN);
                const unsigned short* g = ok ? xcl + (rowbase + (long long)gx * 8)
                                             : (const unsigned short*)zerow;
                bf16x8v dfrag = *(const bf16x8v*)g;
                int tap = (kz * 5 + ky) * 5 + kx;
                const unsigned short* wp = wb + ((size_t)tap << 9) + n * 16 + kc * 8;
                bf16x8v wfrag = *(const bf16x8v*)wp;
                acc = __builtin_amdgcn_mfma_f32_32x32x16_bf16(wfrag, dfrag, acc, 0, 0, 0);
            }
        }
    }

    int sp = (oz * DOUT + oy) * DOUT + ox;
    float mval = mask[b * DOUT * DOUT * DOUT + sp];
#pragma unroll
    for (int q = 0; q < 4; ++q) {
        int co0 = 8 * q + 4 * kc;
        bf16x4v s4;
#pragma unroll
        for (int j = 0; j < 4; ++j) {
            int co = co0 + j;
            float v = (acc[4 * q + j] + bias[co]) * mval;
            t1[(size_t)(b * 32 + co) * 32768 + sp] = v;
            s4[j] = (short)f2bf(v * v);
        }
        *(bf16x4v*)(sqcl + ((size_t)(b * 32768 + sp)) * 32 + co0) = s4;
    }
}

// ===== fused GDN1 epilogue -> PLANAR y1 [pl4][b][vox][16] bf16 =====
// GDN1 mconv is CIG=2 (R19 revert: 1024 blocks, 24.6KB LDS — the R11 optimum;
// CIG=1's halved grid + doubled LDS cost ~12us of latency-hiding for a 3us
// traffic saving). Sums 2 den partials.
__global__ __launch_bounds__(128) void gdn_cl1_kernel(const float* __restrict__ t,
        const float* __restrict__ pd, const float* __restrict__ beta,
        const float* __restrict__ scale, unsigned short* __restrict__ y1p) {
    constexpr size_t NTOT = (size_t)Bn * 32 * 32768;
    constexpr size_t PLSZ = (size_t)Bn * 32768 * 16;   // shorts per plane
    int idx = blockIdx.x * 128 + threadIdx.x;   // < 65536 = Bn*32^3
    int sp = idx & 32767; int b = idx >> 15;
    float sc = scale[b];
    bf16x8v hi[4], lo[4];
#pragma unroll
    for (int g = 0; g < 4; ++g) {
#pragma unroll
        for (int j = 0; j < 8; ++j) {
            int ci = g * 8 + j;
            size_t p = (size_t)(b * 32 + ci) * 32768 + sp;
            float den = pd[p] + pd[NTOT + p];
            float v = t[p] * rsqrtf(beta[ci] + den) * sc;
            unsigned short h = f2bf(v);
            hi[g][j] = (short)h;
            lo[g][j] = (short)f2bf(v - bf2f(h));
        }
    }
    size_t vo = ((size_t)b * 32768 + sp) * 16;
    *(bf16x8v*)(y1p + 0 * PLSZ + vo)     = hi[0];
    *(bf16x8v*)(y1p + 0 * PLSZ + vo + 8) = hi[1];
    *(bf16x8v*)(y1p + 1 * PLSZ + vo)     = hi[2];
    *(bf16x8v*)(y1p + 1 * PLSZ + vo + 8) = hi[3];
    *(bf16x8v*)(y1p + 2 * PLSZ + vo)     = lo[0];
    *(bf16x8v*)(y1p + 2 * PLSZ + vo + 8) = lo[1];
    *(bf16x8v*)(y1p + 3 * PLSZ + vo)     = lo[2];
    *(bf16x8v*)(y1p + 3 * PLSZ + vo + 8) = lo[3];
}

// ===== fused GDN2 epilogue + CL hi/lo/hi transform (64ch); sums 4 den partials =====
__global__ __launch_bounds__(128) void gdn_cl2_kernel(const float* __restrict__ t,
        const float* __restrict__ pd, const float* __restrict__ beta,
        const float* __restrict__ scale, unsigned short* __restrict__ yhl) {
    constexpr size_t NTOT = (size_t)Bn * 64 * 4096;
    int idx = blockIdx.x * 128 + threadIdx.x;   // < 8192 = Bn*16^3
    if (idx >= Bn * 4096) return;
    int sp = idx & 4095; int b = idx >> 12;
    float sc = scale[b];
    bf16x8v blk[24];
#pragma unroll
    for (int g = 0; g < 8; ++g) {
#pragma unroll
        for (int j = 0; j < 8; ++j) {
            int ci = g * 8 + j;
            size_t p = (size_t)(b * 64 + ci) * 4096 + sp;
            float den = pd[p] + pd[NTOT + p] + pd[2 * NTOT + p] + pd[3 * NTOT + p];
            float v = t[p] * rsqrtf(beta[ci] + den) * sc;
            unsigned short h = f2bf(v);
            blk[g][j] = (short)h;
            blk[8 + g][j] = (short)f2bf(v - bf2f(h));
            blk[16 + g][j] = (short)h;
        }
    }
    unsigned short* o = yhl + (size_t)idx * 192;
#pragma unroll
    for (int g = 0; g < 24; ++g) *(bf16x8v*)(o + g * 8) = blk[g];
}

// ===== planar-input stride-2 MFMA conv (conv2) =====
template<int COUTt, int DIN, int DOUT, int CIG, int ZSPL, int PLN>
__global__ __launch_bounds__(256) void mconv_s2p_kernel(
    const unsigned short* __restrict__ in,   // planar bf16
    const unsigned short* __restrict__ wb,   // [cs][nch][tap][n32][kc2][8]
    const float* __restrict__ zerow,
    float* __restrict__ pout)                // [zig*CIG+cs][b][co][vox] plain stores
{
    constexpr int NCH = COUTt / 32;
    constexpr int NTZ = DOUT / 4, NTY = DOUT / 4, NTX = (DOUT >= 8) ? DOUT / 8 : 1;
    constexpr int NT = NTZ * NTY * NTX * Bn;
    constexpr int VOX = DOUT * DOUT * DOUT;
    constexpr size_t PLSZ = (size_t)Bn * DIN * DIN * DIN * 16;

    int tile = blockIdx.x % NT; int rest = blockIdx.x / NT;
    int cs = rest % CIG; int zig = rest / CIG;
    int pl = cs % PLN;
    int r = tile;
    int tx0 = (r % NTX) * 8; r /= NTX;
    int ty0 = (r % NTY) * 4; r /= NTY;
    int tz0 = (r % NTZ) * 4; int b = r / NTZ;

    int tid = threadIdx.x;
    int lane = tid & 63, w = tid >> 6;
    int n = lane & 31, kc = lane >> 5;
    int oz = tz0 + w, oy = ty0 + (n >> 3), ox = tx0 + (n & 7);

    const unsigned short* inp = in + (size_t)pl * PLSZ;

    f32x16v acc[NCH];
#pragma unroll
    for (int c = 0; c < NCH; ++c)
#pragma unroll
        for (int i = 0; i < 16; ++i) acc[c][i] = 0.f;

    int kzlo, kzhi;
    if (ZSPL == 5)      { kzlo = zig;     kzhi = zig + 1; }
    else if (ZSPL == 3) { kzlo = 2 * zig; kzhi = (2 * zig + 2 < 5) ? 2 * zig + 2 : 5; }
    else                { kzlo = 0;       kzhi = 5; }
#pragma unroll 1
    for (int kz = kzlo; kz < kzhi; ++kz) {
        int gz = 2 * oz + kz - 2;
        bool zok = (unsigned)gz < (unsigned)DIN;
#pragma unroll 1
        for (int ky = 0; ky < 5; ++ky) {
            int gy = 2 * oy + ky - 2;
            bool zyok = zok && ((unsigned)gy < (unsigned)DIN);
            long long rowbase = (((long long)(b * DIN + gz) * DIN + gy) * DIN) * 16 + kc * 8;
#pragma unroll
            for (int kx = 0; kx < 5; ++kx) {
                int gx = 2 * ox + kx - 2;
                bool ok = zyok && ((unsigned)gx < (unsigned)DIN);
                const unsigned short* g = ok ? inp + (rowbase + (long long)gx * 16)
                                             : (const unsigned short*)zerow;
                bf16x8v dfrag = *(const bf16x8v*)g;
                int tap = (kz * 5 + ky) * 5 + kx;
#pragma unroll
                for (int c = 0; c < NCH; ++c) {
                    const unsigned short* wp =
                        wb + (((size_t)(cs * NCH + c) * 125 + tap) << 9) + n * 16 + kc * 8;
                    bf16x8v wfrag = *(const bf16x8v*)wp;
                    acc[c] = __builtin_amdgcn_mfma_f32_32x32x16_bf16(wfrag, dfrag, acc[c], 0, 0, 0);
                }
            }
        }
    }

    int sp = (oz * DOUT + oy) * DOUT + ox;
#pragma unroll
    for (int c = 0; c < NCH; ++c) {
#pragma unroll
        for (int rr = 0; rr < 16; ++rr) {
            int co = c * 32 + (rr & 3) + 8 * (rr >> 2) + 4 * kc;
            pout[((size_t)((zig * CIG + cs) * Bn + b) * COUTt + co) * VOX + sp] = acc[c][rr];
        }
    }
}

// ===== stride-2 MFMA conv, channel-last input (conv3) =====
template<int CINe, int COUTt, int DIN, int DOUT, int CIG, int ZSPL>
__global__ __launch_bounds__(256) void mconv_s2_kernel(
    const unsigned short* __restrict__ in,   // CL bf16 [b][z][y][x][CINe]
    const unsigned short* __restrict__ wb,   // [cs][nch][tap][n32][kc2][8]
    const float* __restrict__ zerow,
    float* __restrict__ pout)                // [zig*CIG+cs][b][co][vox] plain stores
{
    constexpr int NCH = COUTt / 32;
    constexpr int NTZ = DOUT / 4, NTY = DOUT / 4, NTX = (DOUT >= 8) ? DOUT / 8 : 1;
    constexpr int NT = NTZ * NTY * NTX * Bn;
    constexpr int VOX = DOUT * DOUT * DOUT;

    int tile = blockIdx.x % NT; int rest = blockIdx.x / NT;
    int cs = rest % CIG; int zig = rest / CIG;
    int r = tile;
    int tx0 = (r % NTX) * 8; r /= NTX;
    int ty0 = (r % NTY) * 4; r /= NTY;
    int tz0 = (r % NTZ) * 4; int b = r / NTZ;

    int tid = threadIdx.x;
    int lane = tid & 63, w = tid >> 6;
    int n = lane & 31, kc = lane >> 5;
    int oz = tz0 + w, oy = ty0 + (n >> 3), ox = tx0 + (n & 7);

    f32x16v acc[NCH];
#pragma unroll
    for (int c = 0; c < NCH; ++c)
#pragma unroll
        for (int i = 0; i < 16; ++i) acc[c][i] = 0.f;

    int kzlo, kzhi;
    if (ZSPL == 5)      { kzlo = zig;     kzhi = zig + 1; }
    else if (ZSPL == 3) { kzlo = 2 * zig; kzhi = (2 * zig + 2 < 5) ? 2 * zig + 2 : 5; }
    else                { kzlo = 0;       kzhi = 5; }
#pragma unroll 1
    for (int kz = kzlo; kz < kzhi; ++kz) {
        int gz = 2 * oz + kz - 2;
        bool zok = (unsigned)gz < (unsigned)DIN;
#pragma unroll 1
        for (int ky = 0; ky < 5; ++ky) {
            int gy = 2 * oy + ky - 2;
            bool zyok = zok && ((unsigned)gy < (unsigned)DIN);
            long long rowbase = (((long long)(b * DIN + gz) * DIN + gy) * DIN) * CINe
                                + cs * 16 + kc * 8;
#pragma unroll
            for (int kx = 0; kx < 5; ++kx) {
                int gx = 2 * ox + kx - 2;
                bool ok = zyok && ((unsigned)gx < (unsigned)DIN);
                const unsigned short* g = ok ? in + (rowbase + (long long)gx * CINe)
                                             : (const unsigned short*)zerow;
                bf16x8v dfrag = *(const bf16x8v*)g;
                int tap = (kz * 5 + ky) * 5 + kx;
#pragma unroll
                for (int c = 0; c < NCH; ++c) {
                    const unsigned short* wp =
                        wb + (((size_t)(cs * NCH + c) * 125 + tap) << 9) + n * 16 + kc * 8;
                    bf16x8v wfrag = *(const bf16x8v*)wp;
                    acc[c] = __builtin_amdgcn_mfma_f32_32x32x16_bf16(wfrag, dfrag, acc[c], 0, 0, 0);
                }
            }
        }
    }

    int sp = (oz * DOUT + oy) * DOUT + ox;
#pragma unroll
    for (int c = 0; c < NCH; ++c) {
#pragma unroll
        for (int rr = 0; rr < 16; ++rr) {
            int co = c * 32 + (rr & 3) + 8 * (rr >> 2) + 4 * kc;
            pout[((size_t)((zig * CIG + cs) * Bn + b) * COUTt + co) * VOX + sp] = acc[c][rr];
        }
    }
}

// reduce split-K partials + bias + mask -> t fp32 NCDHW, and sq CL bf16
template<int CS, int COUTt, int VOX>
__global__ __launch_bounds__(256) void red_epi_kernel(const float* __restrict__ P,
        const float* __restrict__ bias, const float* __restrict__ mask,
        float* __restrict__ buf, unsigned short* __restrict__ sqcl) {
    constexpr int NTOT = Bn * COUTt * VOX;
    int idx = blockIdx.x * 256 + threadIdx.x;
    if (idx >= NTOT) return;
    int sp = idx % VOX;
    int co = (idx / VOX) % COUTt;
    int b = idx / (VOX * COUTt);
    float s = 0.f;
#pragma unroll
    for (int k = 0; k < CS; ++k) s += P[(size_t)k * NTOT + idx];
    float v = (s + bias[co]) * mask[b * VOX + sp];
    buf[idx] = v;
    sqcl[((size_t)b * VOX + sp) * COUTt + co] = f2bf(v * v);
}

// ===== MFMA conv (stride-1): GDN denominators + conv4 =====
// Plain-store partials [g][b][co][vox]. csl-major LDS layout (degenerates to
// the proven layout at CSPB=1, which all current instantiations use).
template<int CINt, int COUTt, int Dd, int TZ, int YB, int CIG, int ZSPL>
__global__ __launch_bounds__(256) void mconv_kernel(
    const unsigned short* __restrict__ in,   // CL bf16 [b][z][y][x][CINt]
    const unsigned short* __restrict__ wb,
    const float* __restrict__ zerow,
    float* __restrict__ pout)                // [g][b][co][vox] plain stores
{
    constexpr int NCH = COUTt / 32;
    constexpr int CSPB = (CINt / 16) / CIG;    // cs-groups per block
    constexpr int CHS = CSPB * 16;             // shorts per voxel in global CL
    constexpr int LZ = TZ + 4, LYH = YB * 4 + 4, LXH = 12;
    constexpr int HV = LZ * LYH * LXH;
    constexpr int UNP = 2 * HV;                // 16B units per csl plane
    constexpr int UN = CSPB * UNP;             // total 16B units
    constexpr int NLOAD = (UN + 255) / 256;
    constexpr int NTZ = Dd / TZ, NTY = Dd / (YB * 4), NTX = Dd / 8;
    constexpr int NT = NTZ * NTY * NTX * Bn;
    constexpr int VOX = Dd * Dd * Dd;
    __shared__ unsigned short lds[NLOAD * 256 * 8];

    int bid = blockIdx.x;
    int tile = bid % NT; int rest = bid / NT;
    int cs = rest % CIG; int zig = rest / CIG;
    int r = tile;
    int tx0 = (r % NTX) * 8; r /= NTX;
    int ty0 = (r % NTY) * (YB * 4); r /= NTY;
    int tz0 = (r % NTZ) * TZ; int b = r / NTZ;

    int tid = threadIdx.x;
    int iz0 = tz0 - 2, iy0 = ty0 - 2, ix0 = tx0 - 2;
#pragma unroll
    for (int k = 0; k < NLOAD; ++k) {
        int u = tid + k * 256;
        int csl = u / UNP;                     // plane index (csl-major)
        int rem = u % UNP;
        int v = rem >> 1, half = rem & 1;
        int lx = v % LXH; int t = v / LXH;
        int ly = t % LYH, lz = t / LYH;
        int gz = iz0 + lz, gy = iy0 + ly, gx = ix0 + lx;
        bool valid = (csl < CSPB) && (v < HV) &&
                     (unsigned)gz < (unsigned)Dd && (unsigned)gy < (unsigned)Dd &&
                     (unsigned)gx < (unsigned)Dd;
        const unsigned short* g = valid
            ? in + ((((size_t)b * Dd + gz) * Dd + gy) * Dd + gx) * CINt
                 + cs * CHS + csl * 16 + half * 8
            : (const unsigned short*)zerow;
        async_copy16((const float*)g, (float*)&lds[(size_t)u * 8]);
    }
    __syncthreads();

    int lane = tid & 63, w = tid >> 6;
    int zz = (YB == 1) ? w : (w >> 1);
    int yb = (YB == 1) ? 0 : (w & 1);
    int n = lane & 31, kc = lane >> 5;
    int vy = yb * 4 + (n >> 3), vx = n & 7;

    f32x16v acc[NCH];
#pragma unroll
    for (int c = 0; c < NCH; ++c)
#pragma unroll
        for (int i = 0; i < 16; ++i) acc[c][i] = 0.f;

    int kzlo = (ZSPL == 5) ? zig : 0;
    int kzhi = (ZSPL == 5) ? zig + 1 : 5;
#pragma unroll 1
    for (int csl = 0; csl < CSPB; ++csl) {
        int csabs = cs * CSPB + csl;
        const unsigned short* lplane = &lds[(size_t)csl * HV * 16];
#pragma unroll 1
        for (int kz = kzlo; kz < kzhi; ++kz) {
#pragma unroll 1
            for (int ky = 0; ky < 5; ++ky) {
                int hvrow = ((zz + kz) * LYH + (vy + ky)) * LXH + vx;
#pragma unroll
                for (int kx = 0; kx < 5; ++kx) {
                    bf16x8v dfrag = *(const bf16x8v*)&lplane[(size_t)(hvrow + kx) * 16 + kc * 8];
                    int tap = (kz * 5 + ky) * 5 + kx;
#pragma unroll
                    for (int c = 0; c < NCH; ++c) {
                        const unsigned short* wp =
                            wb + (((size_t)(csabs * NCH + c) * 125 + tap) << 9) + n * 16 + kc * 8;
                        bf16x8v wfrag = *(const bf16x8v*)wp;
                        acc[c] = __builtin_amdgcn_mfma_f32_32x32x16_bf16(wfrag, dfrag, acc[c], 0, 0, 0);
                    }
                }
            }
        }
    }

    int g = rest;                            // zig*CIG + cs
    int sp = ((tz0 + zz) * Dd + (ty0 + vy)) * Dd + (tx0 + vx);
#pragma unroll
    for (int c = 0; c < NCH; ++c) {
#pragma unroll
        for (int rr = 0; rr < 16; ++rr) {
            int co = c * 32 + (rr & 3) + 8 * (rr >> 2) + 4 * kc;
            pout[((size_t)(g * Bn + b) * COUTt + co) * VOX + sp] = acc[c][rr];
        }
    }
}

// GDN3 epilogue: sum G den partials, rsqrt, scale -> y3 CL bf16
template<int G, int COUTt, int DOUT>
__global__ __launch_bounds__(256) void gdn_red_cl_kernel(const float* __restrict__ t,
        const float* __restrict__ pd, const float* __restrict__ beta,
        const float* __restrict__ scale, unsigned short* __restrict__ ycl) {
    constexpr int VOX = DOUT * DOUT * DOUT;
    constexpr int NTOT = Bn * COUTt * VOX;
    int idx = blockIdx.x * 256 + threadIdx.x;
    if (idx >= NTOT) return;
    int sp = idx % VOX;
    int co = (idx / VOX) % COUTt;
    int b = idx / (VOX * COUTt);
    float den = 0.f;
#pragma unroll
    for (int k = 0; k < G; ++k) den += pd[(size_t)k * NTOT + idx];
    float v = t[idx] * rsqrtf(beta[co] + den) * scale[b];
    ycl[((size_t)b * VOX + sp) * COUTt + co] = f2bf(v);
}

// conv4 epilogue: sum G conv partials + bias + mask -> out fp32
template<int G, int COUTt, int DOUT>
__global__ __launch_bounds__(256) void conv_red_kernel(const float* __restrict__ pc,
        const float* __restrict__ bias, const float* __restrict__ mask,
        float* __restrict__ outx) {
    constexpr int VOX = DOUT * DOUT * DOUT;
    constexpr int NTOT = Bn * COUTt * VOX;
    int idx = blockIdx.x * 256 + threadIdx.x;
    if (idx >= NTOT) return;
    int sp = idx % VOX;
    int co = (idx / VOX) % COUTt;
    int b = idx / (VOX * COUTt);
    float s = 0.f;
#pragma unroll
    for (int k = 0; k < G; ++k) s += pc[(size_t)k * NTOT + idx];
    outx[idx] = (s + bias[co]) * mask[b * VOX + sp];
}

extern "C" void kernel_launch(void* const* d_in, const int* in_sizes, int n_in,
                              void* d_out, int out_size, void* d_ws, size_t ws_size,
                              hipStream_t stream) {
    const float* x_feat = (const float*)d_in[0];
    const float* QF     = (const float*)d_in[2];
    const float* w1 = (const float*)d_in[3];  const float* b1 = (const float*)d_in[4];
    const float* w2 = (const float*)d_in[5];  const float* b2 = (const float*)d_in[6];
    const float* w3 = (const float*)d_in[7];  const float* b3 = (const float*)d_in[8];
    const float* w4 = (const float*)d_in[9];  const float* b4 = (const float*)d_in[10];
    const float* beta1 = (const float*)d_in[11]; const float* gamma1 = (const float*)d_in[12];
    const float* beta2 = (const float*)d_in[13]; const float* gamma2 = (const float*)d_in[14];
    const float* beta3 = (const float*)d_in[15]; const float* gamma3 = (const float*)d_in[16];

    float* out = (float*)d_out;
    float* ws = (float*)d_ws;
    float* cnt   = ws + OFF_CNT;
    float* zerow = ws + OFF_ZERO;
    float* scale = ws + OFF_SCALE;
    float* m1 = ws + OFF_M1;  float* m2 = ws + OFF_M2;  float* m3 = ws + OFF_M3;
    float* t1 = ws + OFF_T1;
    float* t2 = ws + OFF_T2;
    float* t3 = ws + OFF_T3;
    float* pu = ws + OFF_PU;            // union partial buffer (all split-K producers)
    unsigned short* sq1 = (unsigned short*)(ws + OFF_SQ1);
    unsigned short* sq2 = (unsigned short*)(ws + OFF_SQ2);
    unsigned short* sq3 = (unsigned short*)(ws + OFF_SQ3);
    unsigned short* y3c = (unsigned short*)(ws + OFF_Y3C);
    unsigned short* y1p = (unsigned short*)(ws + OFF_Y1P);
    unsigned short* y2hl = (unsigned short*)(ws + OFF_Y2HL);
    unsigned short* xcl = (unsigned short*)(ws + OFF_Y1);
    unsigned short* wb1 = (unsigned short*)(ws + OFF_WB1);
    unsigned short* wb2 = (unsigned short*)(ws + OFF_WB2);
    unsigned short* wb3 = (unsigned short*)(ws + OFF_WB3);
    unsigned short* wb4 = (unsigned short*)(ws + OFF_WB4);
    unsigned short* wb1s = (unsigned short*)(ws + OFF_WB1S);
    unsigned short* wb2s = (unsigned short*)(ws + OFF_WB2S);
    unsigned short* wb3s = (unsigned short*)(ws + OFF_WB3S);

    // Only cnt (pool accumulators) + zerow need zeroing; all partials are
    // plain-store-then-reduce, and out is fully overwritten.
    hipMemsetAsync(ws, 0, 16 * sizeof(float), stream);

    qmean_kernel<<<4, 256, 0, stream>>>(QF, out + OUT_Q, scale);
    // fused mask + xcl (single x_feat pass) ; fused pool m2+m3 ; k write
    maskxcl_kernel<<<256, 256, 0, stream>>>(x_feat, m1, cnt + 0, xcl);
    pool23_kernel<<<4, 256, 0, stream>>>(m1, m2, m3, cnt);
    writek_kernel<<<1, 64, 0, stream>>>(cnt, out + OUT_K);

    // all weight transforms in one launch
    wall_kernel<<<(WALL_N + 255) / 256, 256, 0, stream>>>(
        gamma1, gamma2, gamma3, w4, w1, w2, w3, ws);

    // Stage 1: conv1 MFMA s2 split-bf16 (K=16, fused epi -> t1 + sq1CL) ;
    //          GDN1 MFMA CIG=2 (1024 blocks, 2 den partials — R11 optimum) ;
    //          gdn_cl1 sums 2 -> PLANAR y1p
    mconv1_s2_kernel<<<512, 256, 0, stream>>>(xcl, wb1s, b1, m1, zerow, t1, sq1);
    mconv_kernel<32, 32, 32, 4, 1, 2, 1>
        <<<1024, 256, 0, stream>>>(sq1, wb1, zerow, pu);
    gdn_cl1_kernel<<<512, 128, 0, stream>>>(t1, pu, beta1, scale, y1p);

    // Stage 2: conv2 MFMA s2 split-bf16, PLANAR gather (cs x6 -> pl=cs&3,
    //          kz-pairs x3, 1152 blocks) ; reduce 18 + epi ; GDN2 MFMA -> 4
    //          partials ; gdn_cl2 -> y2hl
    mconv_s2p_kernel<64, 32, 16, 6, 3, 4>
        <<<64 * 6 * 3, 256, 0, stream>>>(y1p, wb2s, zerow, pu);
    red_epi_kernel<18, 64, 4096><<<2048, 256, 0, stream>>>(pu, b2, m2, t2, sq2);
    mconv_kernel<64, 64, 16, 4, 1, 4, 1>
        <<<256, 256, 0, stream>>>(sq2, wb2, zerow, pu);
    gdn_cl2_kernel<<<64, 128, 0, stream>>>(t2, pu, beta2, scale, y2hl);

    // Stage 3: conv3 MFMA s2 split-bf16 (cs x12, kz x5) -> pu ; reduce 60 + epi ;
    //          GDN3 MFMA -> 30 partials (pu) ; gdn_red_cl sums -> y3 CL bf16
    mconv_s2_kernel<192, 96, 16, 8, 12, 5>
        <<<8 * 12 * 5, 256, 0, stream>>>(y2hl, wb3s, zerow, pu);
    red_epi_kernel<60, 96, 512><<<384, 256, 0, stream>>>(pu, b3, m3, t3, sq3);
    mconv_kernel<96, 96, 8, 2, 2, 6, 5>
        <<<240, 256, 0, stream>>>(sq3, wb3, zerow, pu);
    gdn_red_cl_kernel<30, 96, 8><<<384, 256, 0, stream>>>(t3, pu, beta3, scale, y3c);

    // Stage 4: conv4 MFMA (96->128, s1) -> 30 partials (pu) ;
    //          conv_red sums + bias + mask -> out
    mconv_kernel<96, 128, 8, 2, 2, 6, 5>
        <<<240, 256, 0, stream>>>(y3c, wb4, zerow, pu);
    conv_red_kernel<30, 128, 8><<<512, 256, 0, stream>>>(pu, b4, m3, out + OUT_X);
}